// Round 8
// baseline (283.539 us; speedup 1.0000x reference)
//
#include <hip/hip_runtime.h>
#include <hip/hip_bf16.h>
#include <math.h>

#define A_TOTAL 159882
#define NGT 20
#define NBLK 625   // ceil(A_TOTAL/256)
#define ANB 4      // anchors per conv group

// level geometry: p6(13) p5(25) p4(50) p3(100) p2(200), 3 anchors/pos
// cumulative anchor offsets: 0, 507, 2382, 9882, 39882, 159882

__device__ __forceinline__ float iou_one(float ax1, float ay1, float ax2, float ay2,
                                         float gx1, float gy1, float gx2, float gy2) {
    float a1 = (ax2 - ax1) * (ay2 - ay1);
    float a2 = (gx2 - gx1) * (gy2 - gy1);
    float ltx = fmaxf(ax1, gx1), lty = fmaxf(ay1, gy1);
    float rbx = fminf(ax2, gx2), rby = fminf(ay2, gy2);
    float w = fmaxf(rbx - ltx, 0.f), h = fmaxf(rby - lty, 0.f);
    float inter = w * h;
    return inter / (a1 + a2 - inter);
}

__device__ __forceinline__ void decode_anchor(int a, int& W, int& aid, int& y, int& x, int& lvl) {
    int off;
    if      (a < 507)   { off = 0;     W = 13;  lvl = 0; }
    else if (a < 2382)  { off = 507;   W = 25;  lvl = 1; }
    else if (a < 9882)  { off = 2382;  W = 50;  lvl = 2; }
    else if (a < 39882) { off = 9882;  W = 100; lvl = 3; }
    else                { off = 39882; W = 200; lvl = 4; }
    int rel = a - off;
    aid = rel % 3;
    int pos = rel / 3;
    y = pos / W; x = pos % W;
}

// ============================ persistent coop path ============================

struct CoopParams {
    const float *f0, *f1, *f2, *f3, *f4, *anchors, *gt;
    const float *w_in, *b_in, *w_obj, *b_obj, *w_del, *b_del;
    float* mv;            // [2][A] per-anchor max IoU
    unsigned* aux;        // [2][A] (code<<30)|(mask<<5)|arg
    float* pmax;          // [2][NBLK][20]
    unsigned* blk_cnt;    // [2][NBLK] (pos<<16)|neg
    int* sel_count;       // [2]
    int* sel;             // [2][256]
    float* lossbuf;       // [2][256][2]
    unsigned* bar;        // barrier state (cnt[8] @ r*16, cnt2 @128, gen @144)
    float* wt;            // transposed weights [576][256][4]
    float* xpart;         // [2][8][256][256]
    float* out;
    int nb;               // grid size (blocks), multiple of 256
};

__global__ void k_initbar(unsigned* bar) {
    if (threadIdx.x < 256) bar[threadIdx.x] = 0u;
}

// software grid barrier: 8-way split arrival + sense reversal, agent-scope atomics
__device__ __forceinline__ void gridbar(unsigned* bar, int nb) {
    __syncthreads();
    if (threadIdx.x == 0) {
        __threadfence();   // release: flush this XCD's dirty L2 to device-coherent point
        unsigned* gen = bar + 144;
        unsigned g = __hip_atomic_load(gen, __ATOMIC_RELAXED, __HIP_MEMORY_SCOPE_AGENT);
        const int r = blockIdx.x & 7;
        const unsigned grpsz = (unsigned)(nb >> 3);
        unsigned a = __hip_atomic_fetch_add(bar + r * 16, 1u, __ATOMIC_ACQ_REL,
                                            __HIP_MEMORY_SCOPE_AGENT);
        if (a + 1u == grpsz) {
            __hip_atomic_store(bar + r * 16, 0u, __ATOMIC_RELAXED, __HIP_MEMORY_SCOPE_AGENT);
            unsigned b = __hip_atomic_fetch_add(bar + 128, 1u, __ATOMIC_ACQ_REL,
                                                __HIP_MEMORY_SCOPE_AGENT);
            if (b + 1u == 8u) {
                __hip_atomic_store(bar + 128, 0u, __ATOMIC_RELAXED, __HIP_MEMORY_SCOPE_AGENT);
                __hip_atomic_fetch_add(gen, 1u, __ATOMIC_RELEASE, __HIP_MEMORY_SCOPE_AGENT);
            }
        }
        while (__hip_atomic_load(gen, __ATOMIC_ACQUIRE, __HIP_MEMORY_SCOPE_AGENT) == g)
            __builtin_amdgcn_s_sleep(2);
    }
    __syncthreads();
}

__global__ __launch_bounds__(256) void k_all(CoopParams p) {
    const int bid = blockIdx.x;
    const int NB = p.nb;
    const int tid = threadIdx.x;
    const int lane = tid & 63, wid = tid >> 6;

    __shared__ float sgt[NGT * 4];
    __shared__ float sred[4][NGT];
    __shared__ float pblk[NGT];
    __shared__ float bestl[NGT];
    __shared__ unsigned long long sscan[8];
    __shared__ int wcnt[8];
    __shared__ __align__(16) float patch[ANB][288];
    __shared__ int sW[ANB], sY[ANB], sX[ANB], sAct[ANB];
    __shared__ const float* sfm[ANB];
    __shared__ float red5[5][4];
    __shared__ float rb[4], rl[4];

    // ---------- phase A: weight transpose + IoU block-max + per-anchor store ----------
    for (int idx = bid * 256 + tid; idx < 147456; idx += NB * 256) {
        int co = idx / 576, k4 = idx - co * 576;
        float4 v = *(const float4*)(p.w_in + (size_t)co * 2304 + k4 * 4);
        ((float4*)p.wt)[(size_t)k4 * 256 + co] = v;
    }
    for (int task = bid; task < 2 * NBLK; task += NB) {
        const int img = task / NBLK, blk = task - img * NBLK;
        __syncthreads();
        if (tid < NGT * 4) sgt[tid] = p.gt[img * NGT * 4 + tid];
        __syncthreads();
        const int a = blk * 256 + tid;
        const bool act = a < A_TOTAL;
        float4 ab = make_float4(0.f, 0.f, 1.f, 1.f);
        if (act) ab = ((const float4*)p.anchors)[a];
        float v[NGT];
        float mval = -1.f; int arg = 0;
        #pragma unroll
        for (int g = 0; g < NGT; g++) {
            float u = act ? iou_one(ab.x, ab.y, ab.z, ab.w,
                                    sgt[g*4], sgt[g*4+1], sgt[g*4+2], sgt[g*4+3]) : 0.f;
            v[g] = u;
            if (u > mval) { mval = u; arg = g; }
        }
        #pragma unroll
        for (int g = 0; g < NGT; g++) {
            float u = v[g];
            #pragma unroll
            for (int o = 32; o > 0; o >>= 1) u = fmaxf(u, __shfl_down(u, o));
            if (lane == 0) sred[wid][g] = u;
        }
        __syncthreads();
        if (tid < NGT) {
            float u = fmaxf(fmaxf(sred[0][tid], sred[1][tid]),
                            fmaxf(sred[2][tid], sred[3][tid]));
            pblk[tid] = u;
            p.pmax[((size_t)img * NBLK + blk) * NGT + tid] = u;
        }
        __syncthreads();
        if (act) {
            unsigned mask = 0;
            #pragma unroll
            for (int g = 0; g < NGT; g++)
                if (v[g] == pblk[g] && v[g] > 0.f) mask |= (1u << g);
            p.mv[(size_t)img * A_TOTAL + a] = mval;
            p.aux[(size_t)img * A_TOTAL + a] = (mask << 5) | (unsigned)arg;
        }
        __syncthreads();
    }
    gridbar(p.bar, NB);

    // ---------- phase C: label (no IoU recompute; per-block best re-reduce) ----------
    for (int task = bid; task < 2 * NBLK; task += NB) {
        const int img = task / NBLK, blk = task - img * NBLK;
        __syncthreads();
        float bl[NGT];
        #pragma unroll
        for (int g = 0; g < NGT; g++) bl[g] = 0.f;
        for (int i = tid; i < NBLK; i += 256) {
            const float* pr = p.pmax + ((size_t)img * NBLK + i) * NGT;
            #pragma unroll
            for (int g = 0; g < NGT; g++) bl[g] = fmaxf(bl[g], pr[g]);
        }
        #pragma unroll
        for (int g = 0; g < NGT; g++) {
            float u = bl[g];
            #pragma unroll
            for (int o = 32; o > 0; o >>= 1) u = fmaxf(u, __shfl_down(u, o));
            if (lane == 0) sred[wid][g] = u;
        }
        if (tid < NGT) pblk[tid] = p.pmax[((size_t)img * NBLK + blk) * NGT + tid];
        __syncthreads();
        if (tid < NGT)
            bestl[tid] = fmaxf(fmaxf(sred[0][tid], sred[1][tid]),
                               fmaxf(sred[2][tid], sred[3][tid]));
        __syncthreads();
        const int a = blk * 256 + tid;
        const bool act = a < A_TOTAL;
        int code = 2;
        if (act) {
            float mval = p.mv[(size_t)img * A_TOTAL + a];
            unsigned ax = p.aux[(size_t)img * A_TOTAL + a];
            unsigned mask = ax >> 5;           // bits 5..24; upper bits are 0 from phase A
            bool lq = false;
            #pragma unroll
            for (int g = 0; g < NGT; g++)
                if (((mask >> g) & 1u) && (pblk[g] == bestl[g])) lq = true;
            if (lq || mval >= 0.7f) code = 1;
            else if (mval < 0.3f)   code = 0;
            p.aux[(size_t)img * A_TOTAL + a] = (ax & 0x01FFFFFFu) | ((unsigned)code << 30);
        }
        unsigned long long bp = __ballot(act && code == 1);
        unsigned long long bn = __ballot(act && code == 0);
        if (lane == 0) { wcnt[wid] = __popcll(bp); wcnt[4 + wid] = __popcll(bn); }
        __syncthreads();
        if (tid == 0) {
            unsigned pp = wcnt[0] + wcnt[1] + wcnt[2] + wcnt[3];
            unsigned nn = wcnt[4] + wcnt[5] + wcnt[6] + wcnt[7];
            p.blk_cnt[img * NBLK + blk] = (pp << 16) | nn;
        }
        __syncthreads();
    }
    gridbar(p.bar, NB);

    // ---------- phase E: per-block self prefix + select ----------
    for (int task = bid; task < 2 * NBLK; task += NB) {
        const int img = task / NBLK, blk = task - img * NBLK;
        __syncthreads();
        unsigned long long tot = 0ULL, pre = 0ULL;
        const int j0 = tid * 3;
        #pragma unroll
        for (int j = 0; j < 3; j++) {
            int i = j0 + j;
            if (i < NBLK) {
                unsigned u = p.blk_cnt[img * NBLK + i];
                unsigned long long w = ((unsigned long long)(u >> 16) << 32) | (u & 0xFFFFu);
                tot += w;
                if (i < blk) pre += w;
            }
        }
        #pragma unroll
        for (int o = 32; o > 0; o >>= 1) {
            tot += __shfl_down(tot, o);
            pre += __shfl_down(pre, o);
        }
        if (lane == 0) { sscan[wid] = tot; sscan[4 + wid] = pre; }
        __syncthreads();
        unsigned long long tota = sscan[0] + sscan[1] + sscan[2] + sscan[3];
        unsigned long long prea = sscan[4] + sscan[5] + sscan[6] + sscan[7];
        int tp = (int)(tota >> 32), tn = (int)(tota & 0xFFFFFFFFull);
        int npos = min(tp, 128), capn = 256 - npos;
        if (blk == 0 && tid == 0) p.sel_count[img] = npos + min(tn, capn);
        int base_p = (int)(prea >> 32), base_n = (int)(prea & 0xFFFFFFFFull);
        const int a = blk * 256 + tid;
        const bool act = a < A_TOTAL;
        int code = act ? (int)(p.aux[(size_t)img * A_TOTAL + a] >> 30) : 2;
        const bool isp = act && code == 1;
        const bool isn = act && code == 0;
        unsigned long long bp = __ballot(isp);
        unsigned long long bn = __ballot(isn);
        if (lane == 0) { wcnt[wid] = __popcll(bp); wcnt[4 + wid] = __popcll(bn); }
        __syncthreads();
        const unsigned long long mlt = (1ULL << lane) - 1ULL;
        int rp = __popcll(bp & mlt), rn = __popcll(bn & mlt);
        for (int w = 0; w < 4; w++)
            if (w < wid) { rp += wcnt[w]; rn += wcnt[4 + w]; }
        if (isp) { int r = base_p + rp; if (r < npos) p.sel[img * 256 + r] = a | (1 << 30); }
        if (isn) { int r = base_n + rn; if (r < capn) p.sel[img * 256 + npos + r] = a; }
        __syncthreads();
    }
    gridbar(p.bar, NB);

    // ---------- phase F: sparse conv partials (transposed weights) ----------
    for (int task = bid; task < 1024; task += NB) {
        const int img = task >> 9;
        const int chunk = (task >> 6) & 7;
        const int slot0 = (task & 63) * ANB;
        const int nsel = p.sel_count[img];
        __syncthreads();
        if (slot0 < nsel) {
            if (tid < ANB) {
                int slot = slot0 + tid;
                bool act = slot < nsel;
                int e = act ? p.sel[img * 256 + slot] : 0;
                int a = e & 0x3FFFFFFF;
                int W, aid, y, x, lvl;
                decode_anchor(a, W, aid, y, x, lvl);
                sW[tid] = W; sY[tid] = y; sX[tid] = x; sAct[tid] = act ? 1 : 0;
                sfm[tid] = (lvl == 0 ? p.f0 : lvl == 1 ? p.f1 : lvl == 2 ? p.f2
                            : lvl == 3 ? p.f3 : p.f4);
            }
            __syncthreads();
            for (int q = tid; q < ANB * 288; q += 256) {
                int aa = q / 288;
                int idx = q - aa * 288;
                int cil = idx / 9;
                int r = idx - cil * 9;
                int ky = r / 3, kx = r - ky * 3;
                int W = sW[aa];
                int yy = sY[aa] + ky - 1, xx = sX[aa] + kx - 1;
                float v = 0.f;
                if (sAct[aa] && yy >= 0 && yy < W && xx >= 0 && xx < W) {
                    int ci = chunk * 32 + cil;
                    v = sfm[aa][(((size_t)img * 256 + ci) * W + yy) * W + xx];
                }
                patch[aa][idx] = v;
            }
            __syncthreads();
            const float4* wt4 = (const float4*)p.wt + (size_t)(chunk * 72) * 256 + tid;
            const float4* p0 = (const float4*)patch[0];
            const float4* p1 = (const float4*)patch[1];
            const float4* p2 = (const float4*)patch[2];
            const float4* p3 = (const float4*)patch[3];
            float acc0 = 0.f, acc1 = 0.f, acc2 = 0.f, acc3 = 0.f;
            #pragma unroll 8
            for (int i = 0; i < 72; i++) {
                float4 w = wt4[(size_t)i * 256];
                float4 q4;
                q4 = p0[i]; acc0 += w.x*q4.x + w.y*q4.y + w.z*q4.z + w.w*q4.w;
                q4 = p1[i]; acc1 += w.x*q4.x + w.y*q4.y + w.z*q4.z + w.w*q4.w;
                q4 = p2[i]; acc2 += w.x*q4.x + w.y*q4.y + w.z*q4.z + w.w*q4.w;
                q4 = p3[i]; acc3 += w.x*q4.x + w.y*q4.y + w.z*q4.z + w.w*q4.w;
            }
            float acc[ANB] = {acc0, acc1, acc2, acc3};
            #pragma unroll
            for (int aa = 0; aa < ANB; aa++) {
                int slot = slot0 + aa;
                if (slot < nsel)
                    p.xpart[(((size_t)img * 8 + chunk) * 256 + slot) * 256 + tid] = acc[aa];
            }
            __syncthreads();
        }
    }
    gridbar(p.bar, NB);

    // ---------- phase G: reduce chunks + heads + per-anchor losses ----------
    for (int task = bid; task < 512; task += NB) {
        const int img = task >> 8, slot = task & 255;
        const int nsel = p.sel_count[img];
        __syncthreads();
        if (slot < nsel) {
            const int e = p.sel[img * 256 + slot];
            const int is_pos = (e >> 30) & 1;
            const int a = e & 0x3FFFFFFF;
            int W, aid, y, x, lvl;
            decode_anchor(a, W, aid, y, x, lvl);
            const int c = tid;
            float s = p.b_in[c];
            #pragma unroll
            for (int ch = 0; ch < 8; ch++)
                s += p.xpart[(((size_t)img * 8 + ch) * 256 + slot) * 256 + c];
            float xf = fmaxf(s, 0.f);
            float part[5];
            part[0] = xf * p.w_obj[aid * 256 + c];
            #pragma unroll
            for (int j = 0; j < 4; j++) part[1 + j] = xf * p.w_del[(aid * 4 + j) * 256 + c];
            #pragma unroll
            for (int o = 32; o > 0; o >>= 1)
                #pragma unroll
                for (int j = 0; j < 5; j++) part[j] += __shfl_down(part[j], o);
            if (lane == 0)
                #pragma unroll
                for (int j = 0; j < 5; j++) red5[j][wid] = part[j];
            __syncthreads();
            if (c == 0) {
                float logit = red5[0][0] + red5[0][1] + red5[0][2] + red5[0][3] + p.b_obj[aid];
                float tgt = is_pos ? 1.f : 0.f;
                float bce = fmaxf(logit, 0.f) - logit * tgt + log1pf(expf(-fabsf(logit)));
                float l1 = 0.f;
                if (is_pos) {
                    float d[4];
                    #pragma unroll
                    for (int j = 0; j < 4; j++)
                        d[j] = red5[1 + j][0] + red5[1 + j][1] + red5[1 + j][2] + red5[1 + j][3]
                               + p.b_del[aid * 4 + j];
                    int m = (int)(p.aux[(size_t)img * A_TOTAL + a] & 31u);
                    const float* sp = p.anchors + (size_t)a * 4;
                    const float* t = p.gt + (size_t)(img * NGT + m) * 4;
                    float sw = sp[2] - sp[0], sh = sp[3] - sp[1];
                    float scx = sp[0] + 0.5f * sw, scy = sp[1] + 0.5f * sh;
                    float tw = t[2] - t[0], th = t[3] - t[1];
                    float tcx = t[0] + 0.5f * tw, tcy = t[1] + 0.5f * th;
                    float g0 = (tcx - scx) / sw, g1 = (tcy - scy) / sh;
                    float g2 = logf(tw / sw),    g3 = logf(th / sh);
                    l1 = fabsf(d[0]-g0) + fabsf(d[1]-g1) + fabsf(d[2]-g2) + fabsf(d[3]-g3);
                }
                p.lossbuf[(img * 256 + slot) * 2 + 0] = bce;
                p.lossbuf[(img * 256 + slot) * 2 + 1] = l1;
            }
            __syncthreads();
        }
    }
    gridbar(p.bar, NB);

    // ---------- phase H: deterministic final reduction ----------
    if (bid == 0) {
        float bce = 0.f, l1 = 0.f;
        for (int e = tid; e < 512; e += 256) {
            int img = e >> 8, slot = e & 255;
            if (slot < p.sel_count[img]) {
                bce += p.lossbuf[e * 2 + 0];
                l1  += p.lossbuf[e * 2 + 1];
            }
        }
        #pragma unroll
        for (int o = 32; o > 0; o >>= 1) {
            bce += __shfl_down(bce, o);
            l1  += __shfl_down(l1, o);
        }
        if (lane == 0) { rb[wid] = bce; rl[wid] = l1; }
        __syncthreads();
        if (tid == 0) {
            p.out[0] = 0.5f * (rb[0] + rb[1] + rb[2] + rb[3]);
            p.out[1] = 0.5f * (rl[0] + rl[1] + rl[2] + rl[3]);
        }
    }
}

// ============================ conventional fallback (round-7 proven) ============================

__global__ void k_init(unsigned int* best, float* out) {
    int t = threadIdx.x;
    if (t < 2 * NGT) best[t] = 0u;
    if (t < 2) out[t] = 0.f;
}

__global__ __launch_bounds__(576) void k_wtrans(const float* __restrict__ w_in,
                                                float* __restrict__ wt) {
    const int co = blockIdx.x;
    const int k4 = threadIdx.x;
    float4 v = *(const float4*)(w_in + (size_t)co * 2304 + k4 * 4);
    ((float4*)wt)[(size_t)k4 * 256 + co] = v;
}

__global__ __launch_bounds__(256) void k_bmax(const float* __restrict__ anchors,
                                              const float* __restrict__ gt,
                                              float* __restrict__ pmax) {
    const int img = blockIdx.y;
    __shared__ float sgt[NGT * 4];
    __shared__ float sred[4][NGT];
    const int tid = threadIdx.x;
    if (tid < NGT * 4) sgt[tid] = gt[img * NGT * 4 + tid];
    __syncthreads();
    const int a = blockIdx.x * 256 + tid;
    float4 ab = make_float4(0.f, 0.f, 1.f, 1.f);
    if (a < A_TOTAL) ab = ((const float4*)anchors)[a];
    const int lane = tid & 63, wid = tid >> 6;
    #pragma unroll
    for (int g = 0; g < NGT; g++) {
        float u = (a < A_TOTAL)
                    ? iou_one(ab.x, ab.y, ab.z, ab.w,
                              sgt[g * 4], sgt[g * 4 + 1], sgt[g * 4 + 2], sgt[g * 4 + 3])
                    : 0.f;
        #pragma unroll
        for (int o = 32; o > 0; o >>= 1) u = fmaxf(u, __shfl_down(u, o));
        if (lane == 0) sred[wid][g] = u;
    }
    __syncthreads();
    if (tid < NGT) {
        float u = fmaxf(fmaxf(sred[0][tid], sred[1][tid]),
                        fmaxf(sred[2][tid], sred[3][tid]));
        pmax[((size_t)img * NBLK + blockIdx.x) * NGT + tid] = u;
    }
}

__global__ void k_bred(const float* __restrict__ pmax, unsigned int* __restrict__ best) {
    const int g = blockIdx.x, img = blockIdx.y;
    const int tid = threadIdx.x;
    float v = 0.f;
    for (int i = tid; i < NBLK; i += 256)
        v = fmaxf(v, pmax[((size_t)img * NBLK + i) * NGT + g]);
    const int lane = tid & 63, wid = tid >> 6;
    #pragma unroll
    for (int o = 32; o > 0; o >>= 1) v = fmaxf(v, __shfl_down(v, o));
    __shared__ float r[4];
    if (lane == 0) r[wid] = v;
    __syncthreads();
    if (tid == 0)
        best[img * NGT + g] = __float_as_uint(fmaxf(fmaxf(r[0], r[1]), fmaxf(r[2], r[3])));
}

__global__ void k_label(const float* __restrict__ anchors, const float* __restrict__ gt,
                        const unsigned int* __restrict__ best,
                        unsigned char* packed, unsigned int* blk_cnt) {
    const int img = blockIdx.y;
    __shared__ float sgt[NGT * 4];
    __shared__ unsigned int sbest[NGT];
    __shared__ int wp[4], wn[4];
    const int tid = threadIdx.x;
    if (tid < NGT * 4) sgt[tid] = gt[img * NGT * 4 + tid];
    if (tid < NGT) sbest[tid] = best[img * NGT + tid];
    __syncthreads();
    const int a = blockIdx.x * blockDim.x + tid;
    const bool act = a < A_TOTAL;
    int code = 2;
    if (act) {
        float4 ab = ((const float4*)anchors)[a];
        float mval = -1.f; int arg = 0; bool lq = false;
        #pragma unroll
        for (int g = 0; g < NGT; g++) {
            float v = iou_one(ab.x, ab.y, ab.z, ab.w,
                              sgt[g * 4], sgt[g * 4 + 1], sgt[g * 4 + 2], sgt[g * 4 + 3]);
            if (v > mval) { mval = v; arg = g; }
            if (__float_as_uint(v) == sbest[g] && v > 0.f) lq = true;
        }
        if (lq || mval >= 0.7f) code = 1;
        else if (mval < 0.3f)   code = 0;
        packed[(size_t)img * A_TOTAL + a] = (unsigned char)((code << 5) | arg);
    }
    unsigned long long bp = __ballot(act && code == 1);
    unsigned long long bn = __ballot(act && code == 0);
    const int lane = tid & 63, wid = tid >> 6;
    if (lane == 0) { wp[wid] = __popcll(bp); wn[wid] = __popcll(bn); }
    __syncthreads();
    if (tid == 0) {
        unsigned int p = wp[0] + wp[1] + wp[2] + wp[3];
        unsigned int n = wn[0] + wn[1] + wn[2] + wn[3];
        blk_cnt[img * NBLK + blockIdx.x] = (p << 16) | n;
    }
}

__global__ void k_offsets(const unsigned int* __restrict__ blk_cnt,
                          unsigned long long* blk_off,
                          int* pos_total, int* sel_count) {
    const int img = blockIdx.x;
    const int t = threadIdx.x;
    const int lane = t & 63, wid = t >> 6;
    unsigned long long c = 0ULL;
    if (t < NBLK) {
        unsigned int u = blk_cnt[img * NBLK + t];
        c = ((unsigned long long)(u >> 16) << 32) | (u & 0xFFFFu);
    }
    unsigned long long v = c;
    #pragma unroll
    for (int off = 1; off < 64; off <<= 1) {
        unsigned long long u = __shfl_up(v, off);
        if (lane >= off) v += u;
    }
    __shared__ unsigned long long wsum[16];
    if (lane == 63) wsum[wid] = v;
    __syncthreads();
    if (wid == 0) {
        unsigned long long w = (lane < 16) ? wsum[lane] : 0ULL;
        #pragma unroll
        for (int off = 1; off < 16; off <<= 1) {
            unsigned long long u = __shfl_up(w, off);
            if (lane >= off) w += u;
        }
        if (lane < 16) wsum[lane] = w;
    }
    __syncthreads();
    unsigned long long excl = v - c + (wid > 0 ? wsum[wid - 1] : 0ULL);
    if (t < NBLK) blk_off[img * NBLK + t] = excl;
    if (t == 1023) {
        unsigned long long tot = wsum[15];
        int tp = (int)(tot >> 32), tn = (int)(tot & 0xFFFFFFFFu);
        int npos = min(tp, 128);
        int nneg = min(tn, 256 - npos);
        pos_total[img] = tp;
        sel_count[img] = npos + nneg;
    }
}

__global__ void k_select(const unsigned char* __restrict__ packed,
                         const unsigned long long* __restrict__ blk_off,
                         const int* __restrict__ pos_total,
                         int* sel) {
    const int img = blockIdx.y;
    const int t = threadIdx.x;
    const int a = blockIdx.x * 256 + t;
    const bool act = a < A_TOTAL;
    int code = 2;
    if (act) code = packed[(size_t)img * A_TOTAL + a] >> 5;
    const bool isp = act && code == 1;
    const bool isn = act && code == 0;
    unsigned long long bp = __ballot(isp);
    unsigned long long bn = __ballot(isn);
    const int lane = t & 63, wid = t >> 6;
    __shared__ int wtp[4], wtn[4];
    if (lane == 0) { wtp[wid] = __popcll(bp); wtn[wid] = __popcll(bn); }
    __syncthreads();
    const unsigned long long mlt = (1ULL << lane) - 1ULL;
    int rp = __popcll(bp & mlt);
    int rn = __popcll(bn & mlt);
    for (int w = 0; w < 4; w++) {
        if (w < wid) { rp += wtp[w]; rn += wtn[w]; }
    }
    unsigned long long bo = blk_off[img * NBLK + blockIdx.x];
    const int base_p = (int)(bo >> 32), base_n = (int)(bo & 0xFFFFFFFFu);
    const int npos = min(pos_total[img], 128);
    const int capn = 256 - npos;
    if (isp) {
        int r = base_p + rp;
        if (r < npos) sel[img * 256 + r] = a | (1 << 30);
    }
    if (isn) {
        int r = base_n + rn;
        if (r < capn) sel[img * 256 + npos + r] = a;
    }
}

template <int TRM>
__device__ __forceinline__ void stage_patches(
    const float* __restrict__ f0, const float* __restrict__ f1,
    const float* __restrict__ f2, const float* __restrict__ f3,
    const float* __restrict__ f4,
    const int* __restrict__ sel, int nsel, int img, int chunk, int slot0,
    float (&patch)[ANB][TRM],
    int (&s_W)[ANB], int (&s_y)[ANB], int (&s_x)[ANB], int (&s_act)[ANB],
    const float* (&s_fm)[ANB]) {
    constexpr int CIP = TRM / 9;
    const int tid = threadIdx.x;
    if (tid < ANB) {
        int slot = slot0 + tid;
        bool act = slot < nsel;
        int e = act ? sel[img * 256 + slot] : 0;
        int a = e & 0x3FFFFFFF;
        int W, aid, y, x, lvl;
        decode_anchor(a, W, aid, y, x, lvl);
        s_W[tid] = W; s_y[tid] = y; s_x[tid] = x; s_act[tid] = act ? 1 : 0;
        s_fm[tid] = (lvl == 0 ? f0 : lvl == 1 ? f1 : lvl == 2 ? f2 : lvl == 3 ? f3 : f4);
    }
    __syncthreads();
    for (int p = tid; p < ANB * TRM; p += 256) {
        int aa = p / TRM;
        int idx = p - aa * TRM;
        int cil = idx / 9;
        int r = idx - cil * 9;
        int ky = r / 3, kx = r - ky * 3;
        int W = s_W[aa];
        int yy = s_y[aa] + ky - 1, xx = s_x[aa] + kx - 1;
        float v = 0.f;
        if (s_act[aa] && yy >= 0 && yy < W && xx >= 0 && xx < W) {
            const float* fm = s_fm[aa];
            int ci = chunk * CIP + cil;
            v = fm[(((size_t)img * 256 + ci) * W + yy) * W + xx];
        }
        patch[aa][idx] = v;
    }
    __syncthreads();
}

template <int NCH>
__global__ __launch_bounds__(256) void k_convT(
    const float* __restrict__ f0, const float* __restrict__ f1,
    const float* __restrict__ f2, const float* __restrict__ f3,
    const float* __restrict__ f4,
    const float* __restrict__ wt,
    const int* __restrict__ sel, const int* __restrict__ sel_count,
    float* __restrict__ xpart) {
    constexpr int CIP = 256 / NCH;
    constexpr int TRM = CIP * 9;
    const int img = blockIdx.z;
    const int chunk = blockIdx.y;
    const int slot0 = blockIdx.x * ANB;
    const int nsel = sel_count[img];
    if (slot0 >= nsel) return;

    __shared__ __align__(16) float patch[ANB][TRM];
    __shared__ int s_W[ANB], s_y[ANB], s_x[ANB], s_act[ANB];
    __shared__ const float* s_fm[ANB];
    stage_patches<TRM>(f0, f1, f2, f3, f4, sel, nsel, img, chunk, slot0,
                       patch, s_W, s_y, s_x, s_act, s_fm);

    const int c = threadIdx.x;
    const float4* wt4 = (const float4*)wt + (size_t)(chunk * (TRM / 4)) * 256 + c;
    const float4* p0 = (const float4*)patch[0];
    const float4* p1 = (const float4*)patch[1];
    const float4* p2 = (const float4*)patch[2];
    const float4* p3 = (const float4*)patch[3];
    float acc0 = 0.f, acc1 = 0.f, acc2 = 0.f, acc3 = 0.f;
    #pragma unroll 8
    for (int i = 0; i < TRM / 4; i++) {
        float4 w = wt4[(size_t)i * 256];
        float4 q;
        q = p0[i]; acc0 += w.x * q.x + w.y * q.y + w.z * q.z + w.w * q.w;
        q = p1[i]; acc1 += w.x * q.x + w.y * q.y + w.z * q.z + w.w * q.w;
        q = p2[i]; acc2 += w.x * q.x + w.y * q.y + w.z * q.z + w.w * q.w;
        q = p3[i]; acc3 += w.x * q.x + w.y * q.y + w.z * q.z + w.w * q.w;
    }
    float acc[ANB] = {acc0, acc1, acc2, acc3};
    #pragma unroll
    for (int aa = 0; aa < ANB; aa++) {
        int slot = slot0 + aa;
        if (slot < nsel)
            xpart[(((size_t)img * NCH + chunk) * 256 + slot) * 256 + c] = acc[aa];
    }
}

template <int NCH>
__global__ __launch_bounds__(256) void k_post(
    const float* __restrict__ xpart,
    const float* __restrict__ anchors, const float* __restrict__ gt,
    const float* __restrict__ b_in,
    const float* __restrict__ w_obj, const float* __restrict__ b_obj,
    const float* __restrict__ w_del, const float* __restrict__ b_del,
    const unsigned char* __restrict__ packed,
    const int* __restrict__ sel, const int* __restrict__ sel_count,
    float* __restrict__ lossbuf) {
    const int img = blockIdx.y;
    const int slot = blockIdx.x;
    const int nsel = sel_count[img];
    if (slot >= nsel) return;
    const int e = sel[img * 256 + slot];
    const int is_pos = (e >> 30) & 1;
    const int a = e & 0x3FFFFFFF;
    int W, aid, y, x, lvl;
    decode_anchor(a, W, aid, y, x, lvl);

    const int c = threadIdx.x;
    float s = b_in[c];
    #pragma unroll
    for (int ch = 0; ch < NCH; ch++)
        s += xpart[(((size_t)img * NCH + ch) * 256 + slot) * 256 + c];
    float xf = fmaxf(s, 0.f);

    float part[5];
    part[0] = xf * w_obj[aid * 256 + c];
    #pragma unroll
    for (int j = 0; j < 4; j++) part[1 + j] = xf * w_del[(aid * 4 + j) * 256 + c];
    const int lane = c & 63, wid = c >> 6;
    __shared__ float red[5][4];
    #pragma unroll
    for (int o = 32; o > 0; o >>= 1)
        #pragma unroll
        for (int j = 0; j < 5; j++) part[j] += __shfl_down(part[j], o);
    if (lane == 0)
        #pragma unroll
        for (int j = 0; j < 5; j++) red[j][wid] = part[j];
    __syncthreads();

    if (c == 0) {
        float logit = red[0][0] + red[0][1] + red[0][2] + red[0][3] + b_obj[aid];
        float tgt = is_pos ? 1.f : 0.f;
        float bce = fmaxf(logit, 0.f) - logit * tgt + log1pf(expf(-fabsf(logit)));
        float l1 = 0.f;
        if (is_pos) {
            float d[4];
            #pragma unroll
            for (int j = 0; j < 4; j++)
                d[j] = red[1 + j][0] + red[1 + j][1] + red[1 + j][2] + red[1 + j][3] + b_del[aid * 4 + j];
            int m = packed[(size_t)img * A_TOTAL + a] & 31;
            const float* sp = anchors + (size_t)a * 4;
            const float* t = gt + (size_t)(img * NGT + m) * 4;
            float sw = sp[2] - sp[0], sh = sp[3] - sp[1];
            float scx = sp[0] + 0.5f * sw, scy = sp[1] + 0.5f * sh;
            float tw = t[2] - t[0], th = t[3] - t[1];
            float tcx = t[0] + 0.5f * tw, tcy = t[1] + 0.5f * th;
            float g0 = (tcx - scx) / sw, g1 = (tcy - scy) / sh;
            float g2 = logf(tw / sw),    g3 = logf(th / sh);
            l1 = fabsf(d[0] - g0) + fabsf(d[1] - g1) + fabsf(d[2] - g2) + fabsf(d[3] - g3);
        }
        lossbuf[(img * 256 + slot) * 2 + 0] = bce;
        lossbuf[(img * 256 + slot) * 2 + 1] = l1;
    }
}

__global__ void k_final(const float* __restrict__ lossbuf,
                        const int* __restrict__ sel_count,
                        float* __restrict__ out) {
    const int t = threadIdx.x;
    const int img = t >> 8, slot = t & 255;
    float bce = 0.f, l1 = 0.f;
    if (slot < sel_count[img]) {
        bce = lossbuf[t * 2 + 0];
        l1  = lossbuf[t * 2 + 1];
    }
    const int lane = t & 63, wid = t >> 6;
    #pragma unroll
    for (int o = 32; o > 0; o >>= 1) {
        bce += __shfl_down(bce, o);
        l1  += __shfl_down(l1, o);
    }
    __shared__ float rb[8], rl[8];
    if (lane == 0) { rb[wid] = bce; rl[wid] = l1; }
    __syncthreads();
    if (t == 0) {
        float sb = 0.f, sl = 0.f;
        #pragma unroll
        for (int w = 0; w < 8; w++) { sb += rb[w]; sl += rl[w]; }
        out[0] = 0.5f * sb;
        out[1] = 0.5f * sl;
    }
}

extern "C" void kernel_launch(void* const* d_in, const int* in_sizes, int n_in,
                              void* d_out, int out_size, void* d_ws, size_t ws_size,
                              hipStream_t stream) {
    const float* f_p6 = (const float*)d_in[0];
    const float* f_p5 = (const float*)d_in[1];
    const float* f_p4 = (const float*)d_in[2];
    const float* f_p3 = (const float*)d_in[3];
    const float* f_p2 = (const float*)d_in[4];
    const float* anchors = (const float*)d_in[5];
    const float* gt      = (const float*)d_in[6];
    const float* w_in  = (const float*)d_in[7];
    const float* b_in  = (const float*)d_in[8];
    const float* w_obj = (const float*)d_in[9];
    const float* b_obj = (const float*)d_in[10];
    const float* w_del = (const float*)d_in[11];
    const float* b_del = (const float*)d_in[12];
    float* out = (float*)d_out;
    char* ws = (char*)d_ws;

    // ---- coop layout ----
    const size_t WS_COOP = 9225984;
    int mbpc = 0;
    hipError_t qe = hipOccupancyMaxActiveBlocksPerMultiprocessor(&mbpc, k_all, 256, 0);
    bool coop_ok = (ws_size >= WS_COOP) && (qe == hipSuccess) && (mbpc >= 1);

    if (coop_ok) {
        CoopParams p;
        p.f0 = f_p6; p.f1 = f_p5; p.f2 = f_p4; p.f3 = f_p3; p.f4 = f_p2;
        p.anchors = anchors; p.gt = gt;
        p.w_in = w_in; p.b_in = b_in; p.w_obj = w_obj; p.b_obj = b_obj;
        p.w_del = w_del; p.b_del = b_del;
        p.mv        = (float*)(ws + 0);
        p.aux       = (unsigned*)(ws + 1280000);
        p.pmax      = (float*)(ws + 2560000);
        p.blk_cnt   = (unsigned*)(ws + 2660032);
        p.sel_count = (int*)(ws + 2665088);
        p.sel       = (int*)(ws + 2665216);
        p.lossbuf   = (float*)(ws + 2667264);
        p.bar       = (unsigned*)(ws + 2671360);
        p.wt        = (float*)(ws + 2672384);
        p.xpart     = (float*)(ws + 5031680);
        p.out = out;
        int NB = mbpc * 256;          // 256 CUs
        if (NB > 1024) NB = 1024;
        p.nb = NB;
        k_initbar<<<1, 256, 0, stream>>>(p.bar);
        k_all<<<NB, 256, 0, stream>>>(p);
        return;
    }

    // ---- conventional fallback (round-7) ----
    unsigned int* best          = (unsigned int*)(ws + 0);
    int* pos_total              = (int*)(ws + 160);
    int* sel_count              = (int*)(ws + 168);
    int* sel                    = (int*)(ws + 192);
    unsigned int* blk_cnt       = (unsigned int*)(ws + 2240);
    unsigned long long* blk_off = (unsigned long long*)(ws + 7296);
    unsigned char* packed       = (unsigned char*)(ws + 17344);
    float* lossbuf              = (float*)(ws + 337152);
    float* xpart                = (float*)(ws + 341248);
    float* pmax                 = (float*)(ws + 341248);
    float* wt                   = (float*)(ws + 341248 + 8u * 2 * 256 * 256 * 4);
    const size_t WS_NEED8  = 341248 + 2u * 8 * 256 * 256 * 4;
    const size_t WS_NEEDWT = WS_NEED8 + 2359296;

    if (ws_size >= WS_NEEDWT) {
        k_wtrans<<<256, 576, 0, stream>>>(w_in, wt);
        k_bmax<<<dim3(NBLK, 2), 256, 0, stream>>>(anchors, gt, pmax);
        k_bred<<<dim3(NGT, 2), 256, 0, stream>>>(pmax, best);
        k_label<<<dim3(NBLK, 2), 256, 0, stream>>>(anchors, gt, best, packed, blk_cnt);
        k_offsets<<<2, 1024, 0, stream>>>(blk_cnt, blk_off, pos_total, sel_count);
        k_select<<<dim3(NBLK, 2), 256, 0, stream>>>(packed, blk_off, pos_total, sel);
        k_convT<8><<<dim3(64, 8, 2), 256, 0, stream>>>(f_p6, f_p5, f_p4, f_p3, f_p2,
                                                       wt, sel, sel_count, xpart);
        k_post<8><<<dim3(256, 2), 256, 0, stream>>>(xpart, anchors, gt, b_in,
                                                    w_obj, b_obj, w_del, b_del,
                                                    packed, sel, sel_count, lossbuf);
        k_final<<<1, 512, 0, stream>>>(lossbuf, sel_count, out);
    }
}

// Round 9
// 69.100 us; speedup vs baseline: 4.1033x; 4.1033x over previous
//
#include <hip/hip_runtime.h>
#include <hip/hip_bf16.h>
#include <math.h>

#define A_TOTAL 159882
#define NGT 20
#define NBLK 625   // ceil(A_TOTAL/256)
#define ANB 4      // anchors per conv block
#define WTBLK 288  // extra blocks (x2 imgs) for weight transpose in K1

// level geometry: p6(13) p5(25) p4(50) p3(100) p2(200), 3 anchors/pos
// cumulative anchor offsets: 0, 507, 2382, 9882, 39882, 159882

__device__ __forceinline__ float iou_one(float ax1, float ay1, float ax2, float ay2,
                                         float gx1, float gy1, float gx2, float gy2) {
    float a1 = (ax2 - ax1) * (ay2 - ay1);
    float a2 = (gx2 - gx1) * (gy2 - gy1);
    float ltx = fmaxf(ax1, gx1), lty = fmaxf(ay1, gy1);
    float rbx = fminf(ax2, gx2), rby = fminf(ay2, gy2);
    float w = fmaxf(rbx - ltx, 0.f), h = fmaxf(rby - lty, 0.f);
    float inter = w * h;
    return inter / (a1 + a2 - inter);
}

__device__ __forceinline__ void decode_anchor(int a, int& W, int& aid, int& y, int& x, int& lvl) {
    int off;
    if      (a < 507)   { off = 0;     W = 13;  lvl = 0; }
    else if (a < 2382)  { off = 507;   W = 25;  lvl = 1; }
    else if (a < 9882)  { off = 2382;  W = 50;  lvl = 2; }
    else if (a < 39882) { off = 9882;  W = 100; lvl = 3; }
    else                { off = 39882; W = 200; lvl = 4; }
    int rel = a - off;
    aid = rel % 3;
    int pos = rel / 3;
    y = pos / W; x = pos % W;
}

// ============ K1: weight transpose (blocks >= NBLK) ∥ IoU block-max (blocks < NBLK) ============
__global__ __launch_bounds__(256) void k1_bmax_wtrans(
    const float* __restrict__ anchors, const float* __restrict__ gt,
    const float* __restrict__ w_in,
    float* __restrict__ pmax, float* __restrict__ wt) {
    const int bx = blockIdx.x, img = blockIdx.y;
    const int tid = threadIdx.x;
    if (bx >= NBLK) {
        // one float4 of w_in per thread: wt[k4][co] = w_in[co][k4]
        int idx = ((bx - NBLK) * 2 + img) * 256 + tid;   // 0..147455
        int co = idx / 576, k4 = idx - co * 576;
        float4 v = *(const float4*)(w_in + (size_t)co * 2304 + k4 * 4);
        ((float4*)wt)[(size_t)k4 * 256 + co] = v;
        return;
    }
    __shared__ float sgt[NGT * 4];
    __shared__ float sred[4][NGT];
    if (tid < NGT * 4) sgt[tid] = gt[img * NGT * 4 + tid];
    __syncthreads();
    const int a = bx * 256 + tid;
    float4 ab = make_float4(0.f, 0.f, 1.f, 1.f);
    if (a < A_TOTAL) ab = ((const float4*)anchors)[a];
    const int lane = tid & 63, wid = tid >> 6;
    #pragma unroll
    for (int g = 0; g < NGT; g++) {
        float u = (a < A_TOTAL)
                    ? iou_one(ab.x, ab.y, ab.z, ab.w,
                              sgt[g * 4], sgt[g * 4 + 1], sgt[g * 4 + 2], sgt[g * 4 + 3])
                    : 0.f;
        #pragma unroll
        for (int o = 32; o > 0; o >>= 1) u = fmaxf(u, __shfl_down(u, o));
        if (lane == 0) sred[wid][g] = u;
    }
    __syncthreads();
    if (tid < NGT) {
        float u = fmaxf(fmaxf(sred[0][tid], sred[1][tid]),
                        fmaxf(sred[2][tid], sred[3][tid]));
        pmax[((size_t)img * NBLK + bx) * NGT + tid] = u;
    }
}

// ============ K2: label + in-block global-best re-reduce (replaces bred+label) ============
__global__ __launch_bounds__(256) void k2_label(
    const float* __restrict__ anchors, const float* __restrict__ gt,
    const float* __restrict__ pmax,
    unsigned char* __restrict__ packed, unsigned int* __restrict__ blk_cnt) {
    const int img = blockIdx.y, blk = blockIdx.x;
    const int tid = threadIdx.x;
    const int lane = tid & 63, wid = tid >> 6;
    __shared__ float sgt[NGT * 4];
    __shared__ float sred[4][NGT];
    __shared__ float bestl[NGT];
    __shared__ int wp[4], wn[4];
    if (tid < NGT * 4) sgt[tid] = gt[img * NGT * 4 + tid];

    // recompute global best_per_gt from pmax (max is order-invariant => bitwise exact)
    float bl[NGT];
    #pragma unroll
    for (int g = 0; g < NGT; g++) bl[g] = 0.f;
    for (int i = tid; i < NBLK; i += 256) {
        const float* pr = pmax + ((size_t)img * NBLK + i) * NGT;
        #pragma unroll
        for (int g = 0; g < NGT; g++) bl[g] = fmaxf(bl[g], pr[g]);
    }
    #pragma unroll
    for (int g = 0; g < NGT; g++) {
        float u = bl[g];
        #pragma unroll
        for (int o = 32; o > 0; o >>= 1) u = fmaxf(u, __shfl_down(u, o));
        if (lane == 0) sred[wid][g] = u;
    }
    __syncthreads();
    if (tid < NGT)
        bestl[tid] = fmaxf(fmaxf(sred[0][tid], sred[1][tid]),
                           fmaxf(sred[2][tid], sred[3][tid]));
    __syncthreads();

    const int a = blk * 256 + tid;
    const bool act = a < A_TOTAL;
    int code = 2;
    if (act) {
        float4 ab = ((const float4*)anchors)[a];
        float mval = -1.f; int arg = 0; bool lq = false;
        #pragma unroll
        for (int g = 0; g < NGT; g++) {
            float v = iou_one(ab.x, ab.y, ab.z, ab.w,
                              sgt[g * 4], sgt[g * 4 + 1], sgt[g * 4 + 2], sgt[g * 4 + 3]);
            if (v > mval) { mval = v; arg = g; }
            if (__float_as_uint(v) == __float_as_uint(bestl[g]) && v > 0.f) lq = true;
        }
        if (lq || mval >= 0.7f) code = 1;
        else if (mval < 0.3f)   code = 0;
        packed[(size_t)img * A_TOTAL + a] = (unsigned char)((code << 5) | arg);
    }
    unsigned long long bp = __ballot(act && code == 1);
    unsigned long long bn = __ballot(act && code == 0);
    if (lane == 0) { wp[wid] = __popcll(bp); wn[wid] = __popcll(bn); }
    __syncthreads();
    if (tid == 0) {
        unsigned int p = wp[0] + wp[1] + wp[2] + wp[3];
        unsigned int n = wn[0] + wn[1] + wn[2] + wn[3];
        blk_cnt[img * NBLK + blk] = (p << 16) | n;
    }
}

// ============ K3: select + per-block self-prefix (replaces offsets+select) ============
__global__ __launch_bounds__(256) void k3_select(
    const unsigned char* __restrict__ packed,
    const unsigned int* __restrict__ blk_cnt,
    int* __restrict__ sel, int* __restrict__ sel_count) {
    const int img = blockIdx.y, blk = blockIdx.x;
    const int tid = threadIdx.x;
    const int lane = tid & 63, wid = tid >> 6;
    __shared__ unsigned long long sscan[8];
    __shared__ int wcnt[8];

    unsigned long long tot = 0ULL, pre = 0ULL;
    const int j0 = tid * 3;
    #pragma unroll
    for (int j = 0; j < 3; j++) {
        int i = j0 + j;
        if (i < NBLK) {
            unsigned u = blk_cnt[img * NBLK + i];
            unsigned long long w = ((unsigned long long)(u >> 16) << 32) | (u & 0xFFFFu);
            tot += w;
            if (i < blk) pre += w;
        }
    }
    #pragma unroll
    for (int o = 32; o > 0; o >>= 1) {
        tot += __shfl_down(tot, o);
        pre += __shfl_down(pre, o);
    }
    if (lane == 0) { sscan[wid] = tot; sscan[4 + wid] = pre; }
    __syncthreads();
    unsigned long long tota = sscan[0] + sscan[1] + sscan[2] + sscan[3];
    unsigned long long prea = sscan[4] + sscan[5] + sscan[6] + sscan[7];
    int tp = (int)(tota >> 32), tn = (int)(tota & 0xFFFFFFFFull);
    int npos = min(tp, 128), capn = 256 - npos;
    if (blk == 0 && tid == 0) sel_count[img] = npos + min(tn, capn);
    int base_p = (int)(prea >> 32), base_n = (int)(prea & 0xFFFFFFFFull);

    const int a = blk * 256 + tid;
    const bool act = a < A_TOTAL;
    int code = act ? (packed[(size_t)img * A_TOTAL + a] >> 5) : 2;
    const bool isp = act && code == 1;
    const bool isn = act && code == 0;
    unsigned long long bp = __ballot(isp);
    unsigned long long bn = __ballot(isn);
    if (lane == 0) { wcnt[wid] = __popcll(bp); wcnt[4 + wid] = __popcll(bn); }
    __syncthreads();
    const unsigned long long mlt = (1ULL << lane) - 1ULL;
    int rp = __popcll(bp & mlt), rn = __popcll(bn & mlt);
    for (int w = 0; w < 4; w++)
        if (w < wid) { rp += wcnt[w]; rn += wcnt[4 + w]; }
    if (isp) { int r = base_p + rp; if (r < npos) sel[img * 256 + r] = a | (1 << 30); }
    if (isn) { int r = base_n + rn; if (r < capn) sel[img * 256 + npos + r] = a; }
}

// ============ K4: sparse conv partials, transposed weights (round-7 proven) ============
template <int TRM>
__device__ __forceinline__ void stage_patches(
    const float* __restrict__ f0, const float* __restrict__ f1,
    const float* __restrict__ f2, const float* __restrict__ f3,
    const float* __restrict__ f4,
    const int* __restrict__ sel, int nsel, int img, int chunk, int slot0,
    float (&patch)[ANB][TRM],
    int (&s_W)[ANB], int (&s_y)[ANB], int (&s_x)[ANB], int (&s_act)[ANB],
    const float* (&s_fm)[ANB]) {
    constexpr int CIP = TRM / 9;
    const int tid = threadIdx.x;
    if (tid < ANB) {
        int slot = slot0 + tid;
        bool act = slot < nsel;
        int e = act ? sel[img * 256 + slot] : 0;
        int a = e & 0x3FFFFFFF;
        int W, aid, y, x, lvl;
        decode_anchor(a, W, aid, y, x, lvl);
        s_W[tid] = W; s_y[tid] = y; s_x[tid] = x; s_act[tid] = act ? 1 : 0;
        s_fm[tid] = (lvl == 0 ? f0 : lvl == 1 ? f1 : lvl == 2 ? f2 : lvl == 3 ? f3 : f4);
    }
    __syncthreads();
    for (int p = tid; p < ANB * TRM; p += 256) {
        int aa = p / TRM;
        int idx = p - aa * TRM;
        int cil = idx / 9;
        int r = idx - cil * 9;
        int ky = r / 3, kx = r - ky * 3;
        int W = s_W[aa];
        int yy = s_y[aa] + ky - 1, xx = s_x[aa] + kx - 1;
        float v = 0.f;
        if (s_act[aa] && yy >= 0 && yy < W && xx >= 0 && xx < W) {
            const float* fm = s_fm[aa];
            int ci = chunk * CIP + cil;
            v = fm[(((size_t)img * 256 + ci) * W + yy) * W + xx];
        }
        patch[aa][idx] = v;
    }
    __syncthreads();
}

template <int NCH>
__global__ __launch_bounds__(256) void k_convT(
    const float* __restrict__ f0, const float* __restrict__ f1,
    const float* __restrict__ f2, const float* __restrict__ f3,
    const float* __restrict__ f4,
    const float* __restrict__ wt,
    const int* __restrict__ sel, const int* __restrict__ sel_count,
    float* __restrict__ xpart) {
    constexpr int CIP = 256 / NCH;
    constexpr int TRM = CIP * 9;
    const int img = blockIdx.z;
    const int chunk = blockIdx.y;
    const int slot0 = blockIdx.x * ANB;
    const int nsel = sel_count[img];
    if (slot0 >= nsel) return;

    __shared__ __align__(16) float patch[ANB][TRM];
    __shared__ int s_W[ANB], s_y[ANB], s_x[ANB], s_act[ANB];
    __shared__ const float* s_fm[ANB];
    stage_patches<TRM>(f0, f1, f2, f3, f4, sel, nsel, img, chunk, slot0,
                       patch, s_W, s_y, s_x, s_act, s_fm);

    const int c = threadIdx.x;
    const float4* wt4 = (const float4*)wt + (size_t)(chunk * (TRM / 4)) * 256 + c;
    const float4* p0 = (const float4*)patch[0];
    const float4* p1 = (const float4*)patch[1];
    const float4* p2 = (const float4*)patch[2];
    const float4* p3 = (const float4*)patch[3];
    float acc0 = 0.f, acc1 = 0.f, acc2 = 0.f, acc3 = 0.f;
    #pragma unroll 8
    for (int i = 0; i < TRM / 4; i++) {
        float4 w = wt4[(size_t)i * 256];      // 1KB contiguous per wave
        float4 q;
        q = p0[i]; acc0 += w.x * q.x + w.y * q.y + w.z * q.z + w.w * q.w;
        q = p1[i]; acc1 += w.x * q.x + w.y * q.y + w.z * q.z + w.w * q.w;
        q = p2[i]; acc2 += w.x * q.x + w.y * q.y + w.z * q.z + w.w * q.w;
        q = p3[i]; acc3 += w.x * q.x + w.y * q.y + w.z * q.z + w.w * q.w;
    }
    float acc[ANB] = {acc0, acc1, acc2, acc3};
    #pragma unroll
    for (int aa = 0; aa < ANB; aa++) {
        int slot = slot0 + aa;
        if (slot < nsel)
            xpart[(((size_t)img * NCH + chunk) * 256 + slot) * 256 + c] = acc[aa];
    }
}

// ============ K5: reduce chunks + heads + per-anchor losses (round-7 proven) ============
template <int NCH>
__global__ __launch_bounds__(256) void k_post(
    const float* __restrict__ xpart,
    const float* __restrict__ anchors, const float* __restrict__ gt,
    const float* __restrict__ b_in,
    const float* __restrict__ w_obj, const float* __restrict__ b_obj,
    const float* __restrict__ w_del, const float* __restrict__ b_del,
    const unsigned char* __restrict__ packed,
    const int* __restrict__ sel, const int* __restrict__ sel_count,
    float* __restrict__ lossbuf) {
    const int img = blockIdx.y;
    const int slot = blockIdx.x;
    const int nsel = sel_count[img];
    if (slot >= nsel) return;
    const int e = sel[img * 256 + slot];
    const int is_pos = (e >> 30) & 1;
    const int a = e & 0x3FFFFFFF;
    int W, aid, y, x, lvl;
    decode_anchor(a, W, aid, y, x, lvl);

    const int c = threadIdx.x;
    float s = b_in[c];
    #pragma unroll
    for (int ch = 0; ch < NCH; ch++)
        s += xpart[(((size_t)img * NCH + ch) * 256 + slot) * 256 + c];
    float xf = fmaxf(s, 0.f);

    float part[5];
    part[0] = xf * w_obj[aid * 256 + c];
    #pragma unroll
    for (int j = 0; j < 4; j++) part[1 + j] = xf * w_del[(aid * 4 + j) * 256 + c];
    const int lane = c & 63, wid = c >> 6;
    __shared__ float red[5][4];
    #pragma unroll
    for (int o = 32; o > 0; o >>= 1)
        #pragma unroll
        for (int j = 0; j < 5; j++) part[j] += __shfl_down(part[j], o);
    if (lane == 0)
        #pragma unroll
        for (int j = 0; j < 5; j++) red[j][wid] = part[j];
    __syncthreads();

    if (c == 0) {
        float logit = red[0][0] + red[0][1] + red[0][2] + red[0][3] + b_obj[aid];
        float tgt = is_pos ? 1.f : 0.f;
        float bce = fmaxf(logit, 0.f) - logit * tgt + log1pf(expf(-fabsf(logit)));
        float l1 = 0.f;
        if (is_pos) {
            float d[4];
            #pragma unroll
            for (int j = 0; j < 4; j++)
                d[j] = red[1 + j][0] + red[1 + j][1] + red[1 + j][2] + red[1 + j][3] + b_del[aid * 4 + j];
            int m = packed[(size_t)img * A_TOTAL + a] & 31;
            const float* sp = anchors + (size_t)a * 4;
            const float* t = gt + (size_t)(img * NGT + m) * 4;
            float sw = sp[2] - sp[0], sh = sp[3] - sp[1];
            float scx = sp[0] + 0.5f * sw, scy = sp[1] + 0.5f * sh;
            float tw = t[2] - t[0], th = t[3] - t[1];
            float tcx = t[0] + 0.5f * tw, tcy = t[1] + 0.5f * th;
            float g0 = (tcx - scx) / sw, g1 = (tcy - scy) / sh;
            float g2 = logf(tw / sw),    g3 = logf(th / sh);
            l1 = fabsf(d[0] - g0) + fabsf(d[1] - g1) + fabsf(d[2] - g2) + fabsf(d[3] - g3);
        }
        lossbuf[(img * 256 + slot) * 2 + 0] = bce;
        lossbuf[(img * 256 + slot) * 2 + 1] = l1;
    }
}

// ============ K6: deterministic final reduction ============
__global__ void k_final(const float* __restrict__ lossbuf,
                        const int* __restrict__ sel_count,
                        float* __restrict__ out) {
    const int t = threadIdx.x;      // 512 threads
    const int img = t >> 8, slot = t & 255;
    float bce = 0.f, l1 = 0.f;
    if (slot < sel_count[img]) {
        bce = lossbuf[t * 2 + 0];
        l1  = lossbuf[t * 2 + 1];
    }
    const int lane = t & 63, wid = t >> 6;
    #pragma unroll
    for (int o = 32; o > 0; o >>= 1) {
        bce += __shfl_down(bce, o);
        l1  += __shfl_down(l1, o);
    }
    __shared__ float rb[8], rl[8];
    if (lane == 0) { rb[wid] = bce; rl[wid] = l1; }
    __syncthreads();
    if (t == 0) {
        float sb = 0.f, sl = 0.f;
        #pragma unroll
        for (int w = 0; w < 8; w++) { sb += rb[w]; sl += rl[w]; }
        out[0] = 0.5f * sb;
        out[1] = 0.5f * sl;
    }
}

// ============ minimal fallback (round-3 proven) for tiny workspace ============
__global__ void k_init(unsigned int* best, float* out) {
    int t = threadIdx.x;
    if (t < 2 * NGT) best[t] = 0u;
    if (t < 2) out[t] = 0.f;
}

__global__ void k_best(const float* __restrict__ anchors, const float* __restrict__ gt,
                       unsigned int* best) {
    const int img = blockIdx.y;
    __shared__ float sgt[NGT * 4];
    __shared__ float sred[4][NGT];
    const int tid = threadIdx.x;
    if (tid < NGT * 4) sgt[tid] = gt[img * NGT * 4 + tid];
    __syncthreads();
    float vmax[NGT];
    #pragma unroll
    for (int g = 0; g < NGT; g++) vmax[g] = 0.f;
    const int stride = gridDim.x * blockDim.x;
    for (int a = blockIdx.x * blockDim.x + tid; a < A_TOTAL; a += stride) {
        float4 ab = ((const float4*)anchors)[a];
        #pragma unroll
        for (int g = 0; g < NGT; g++) {
            float v = iou_one(ab.x, ab.y, ab.z, ab.w,
                              sgt[g * 4], sgt[g * 4 + 1], sgt[g * 4 + 2], sgt[g * 4 + 3]);
            vmax[g] = fmaxf(vmax[g], v);
        }
    }
    const int lane = tid & 63, wid = tid >> 6;
    #pragma unroll
    for (int g = 0; g < NGT; g++) {
        float v = vmax[g];
        #pragma unroll
        for (int o = 32; o > 0; o >>= 1) v = fmaxf(v, __shfl_down(v, o));
        if (lane == 0) sred[wid][g] = v;
    }
    __syncthreads();
    if (tid < NGT) {
        float v = fmaxf(fmaxf(sred[0][tid], sred[1][tid]),
                        fmaxf(sred[2][tid], sred[3][tid]));
        atomicMax(&best[img * NGT + tid], __float_as_uint(v));
    }
}

__global__ void k_label_old(const float* __restrict__ anchors, const float* __restrict__ gt,
                            const unsigned int* __restrict__ best,
                            unsigned char* packed, unsigned int* blk_cnt) {
    const int img = blockIdx.y;
    __shared__ float sgt[NGT * 4];
    __shared__ unsigned int sbest[NGT];
    __shared__ int wp[4], wn[4];
    const int tid = threadIdx.x;
    if (tid < NGT * 4) sgt[tid] = gt[img * NGT * 4 + tid];
    if (tid < NGT) sbest[tid] = best[img * NGT + tid];
    __syncthreads();
    const int a = blockIdx.x * blockDim.x + tid;
    const bool act = a < A_TOTAL;
    int code = 2;
    if (act) {
        float4 ab = ((const float4*)anchors)[a];
        float mval = -1.f; int arg = 0; bool lq = false;
        #pragma unroll
        for (int g = 0; g < NGT; g++) {
            float v = iou_one(ab.x, ab.y, ab.z, ab.w,
                              sgt[g * 4], sgt[g * 4 + 1], sgt[g * 4 + 2], sgt[g * 4 + 3]);
            if (v > mval) { mval = v; arg = g; }
            if (__float_as_uint(v) == sbest[g] && v > 0.f) lq = true;
        }
        if (lq || mval >= 0.7f) code = 1;
        else if (mval < 0.3f)   code = 0;
        packed[(size_t)img * A_TOTAL + a] = (unsigned char)((code << 5) | arg);
    }
    unsigned long long bp = __ballot(act && code == 1);
    unsigned long long bn = __ballot(act && code == 0);
    const int lane = tid & 63, wid = tid >> 6;
    if (lane == 0) { wp[wid] = __popcll(bp); wn[wid] = __popcll(bn); }
    __syncthreads();
    if (tid == 0) {
        unsigned int p = wp[0] + wp[1] + wp[2] + wp[3];
        unsigned int n = wn[0] + wn[1] + wn[2] + wn[3];
        blk_cnt[img * NBLK + blockIdx.x] = (p << 16) | n;
    }
}

__global__ __launch_bounds__(256) void k_eval(
    const float* __restrict__ f0, const float* __restrict__ f1,
    const float* __restrict__ f2, const float* __restrict__ f3,
    const float* __restrict__ f4,
    const float* __restrict__ anchors, const float* __restrict__ gt,
    const float* __restrict__ w_in, const float* __restrict__ b_in,
    const float* __restrict__ w_obj, const float* __restrict__ b_obj,
    const float* __restrict__ w_del, const float* __restrict__ b_del,
    const unsigned char* __restrict__ packed,
    const int* __restrict__ sel, const int* __restrict__ sel_count,
    float* out) {
    const int img = blockIdx.x >> 6;
    const int slot0 = (blockIdx.x & 63) * 4;
    const int nsel = sel_count[img];
    if (slot0 >= nsel) return;

    __shared__ __align__(16) float patch[4][2304];
    __shared__ float red[4][5][4];
    __shared__ float lsum[2];
    const int c = threadIdx.x;
    if (c < 2) lsum[c] = 0.f;

    bool actv[4]; int av[4], aidv[4], isposv[4];
    #pragma unroll
    for (int aa = 0; aa < 4; aa++) {
        int slot = slot0 + aa;
        bool act = slot < nsel;
        actv[aa] = act;
        int e = act ? sel[img * 256 + slot] : 0;
        isposv[aa] = (e >> 30) & 1;
        int a = e & 0x3FFFFFFF;
        av[aa] = a;
        int W, aid, y, x, lvl;
        decode_anchor(a, W, aid, y, x, lvl);
        aidv[aa] = aid;
        const float* fm = lvl == 0 ? f0 : lvl == 1 ? f1 : lvl == 2 ? f2 : lvl == 3 ? f3 : f4;
        const float* ch = fm + ((size_t)img * 256 + c) * W * W;
        #pragma unroll
        for (int ky = 0; ky < 3; ky++)
            #pragma unroll
            for (int kx = 0; kx < 3; kx++) {
                int yy = y + ky - 1, xx = x + kx - 1;
                float v = (act && yy >= 0 && yy < W && xx >= 0 && xx < W) ? ch[yy * W + xx] : 0.f;
                patch[aa][c * 9 + ky * 3 + kx] = v;
            }
    }
    __syncthreads();

    const float bi = b_in[c];
    float acc0 = bi, acc1 = bi, acc2 = bi, acc3 = bi;
    const float4* wr = (const float4*)(w_in + (size_t)c * 2304);
    const float4* p0 = (const float4*)patch[0];
    const float4* p1 = (const float4*)patch[1];
    const float4* p2 = (const float4*)patch[2];
    const float4* p3 = (const float4*)patch[3];
    #pragma unroll 4
    for (int i = 0; i < 576; i++) {
        float4 w = wr[i];
        float4 q;
        q = p0[i]; acc0 += w.x * q.x + w.y * q.y + w.z * q.z + w.w * q.w;
        q = p1[i]; acc1 += w.x * q.x + w.y * q.y + w.z * q.z + w.w * q.w;
        q = p2[i]; acc2 += w.x * q.x + w.y * q.y + w.z * q.z + w.w * q.w;
        q = p3[i]; acc3 += w.x * q.x + w.y * q.y + w.z * q.z + w.w * q.w;
    }
    float xf[4] = { fmaxf(acc0, 0.f), fmaxf(acc1, 0.f), fmaxf(acc2, 0.f), fmaxf(acc3, 0.f) };

    float part[4][5];
    #pragma unroll
    for (int aa = 0; aa < 4; aa++) {
        part[aa][0] = xf[aa] * w_obj[aidv[aa] * 256 + c];
        #pragma unroll
        for (int j = 0; j < 4; j++)
            part[aa][1 + j] = xf[aa] * w_del[(aidv[aa] * 4 + j) * 256 + c];
    }
    const int lane = c & 63, wid = c >> 6;
    #pragma unroll
    for (int o = 32; o > 0; o >>= 1)
        #pragma unroll
        for (int aa = 0; aa < 4; aa++)
            #pragma unroll
            for (int j = 0; j < 5; j++)
                part[aa][j] += __shfl_down(part[aa][j], o);
    if (lane == 0)
        #pragma unroll
        for (int aa = 0; aa < 4; aa++)
            #pragma unroll
            for (int j = 0; j < 5; j++)
                red[aa][j][wid] = part[aa][j];
    __syncthreads();

    if (c < 4 && actv[c]) {
        const int aa = c;
        float logit = red[aa][0][0] + red[aa][0][1] + red[aa][0][2] + red[aa][0][3] + b_obj[aidv[aa]];
        float tgt = isposv[aa] ? 1.f : 0.f;
        float bce = fmaxf(logit, 0.f) - logit * tgt + log1pf(expf(-fabsf(logit)));
        atomicAdd(&lsum[0], bce);
        if (isposv[aa]) {
            float d[4];
            #pragma unroll
            for (int j = 0; j < 4; j++)
                d[j] = red[aa][1 + j][0] + red[aa][1 + j][1] + red[aa][1 + j][2] + red[aa][1 + j][3]
                       + b_del[aidv[aa] * 4 + j];
            int a = av[aa];
            int m = packed[(size_t)img * A_TOTAL + a] & 31;
            const float* s = anchors + (size_t)a * 4;
            const float* t = gt + (size_t)(img * NGT + m) * 4;
            float sw = s[2] - s[0], sh = s[3] - s[1];
            float scx = s[0] + 0.5f * sw, scy = s[1] + 0.5f * sh;
            float tw = t[2] - t[0], th = t[3] - t[1];
            float tcx = t[0] + 0.5f * tw, tcy = t[1] + 0.5f * th;
            float g0 = (tcx - scx) / sw, g1 = (tcy - scy) / sh;
            float g2 = logf(tw / sw),    g3 = logf(th / sh);
            float l1 = fabsf(d[0] - g0) + fabsf(d[1] - g1) + fabsf(d[2] - g2) + fabsf(d[3] - g3);
            atomicAdd(&lsum[1], l1);
        }
    }
    __syncthreads();
    if (c == 0) {
        atomicAdd(&out[0], 0.5f * lsum[0]);
        atomicAdd(&out[1], 0.5f * lsum[1]);
    }
}

extern "C" void kernel_launch(void* const* d_in, const int* in_sizes, int n_in,
                              void* d_out, int out_size, void* d_ws, size_t ws_size,
                              hipStream_t stream) {
    const float* f_p6 = (const float*)d_in[0];
    const float* f_p5 = (const float*)d_in[1];
    const float* f_p4 = (const float*)d_in[2];
    const float* f_p3 = (const float*)d_in[3];
    const float* f_p2 = (const float*)d_in[4];
    const float* anchors = (const float*)d_in[5];
    const float* gt      = (const float*)d_in[6];
    const float* w_in  = (const float*)d_in[7];
    const float* b_in  = (const float*)d_in[8];
    const float* w_obj = (const float*)d_in[9];
    const float* b_obj = (const float*)d_in[10];
    const float* w_del = (const float*)d_in[11];
    const float* b_del = (const float*)d_in[12];
    float* out = (float*)d_out;
    char* ws = (char*)d_ws;

    // workspace layout (round-7 offsets)
    unsigned int* best    = (unsigned int*)(ws + 0);      // fallback only
    int* sel_count        = (int*)(ws + 168);             // 8 B
    int* sel              = (int*)(ws + 192);             // 2048 B
    unsigned int* blk_cnt = (unsigned int*)(ws + 2240);   // 5000 B
    unsigned char* packed = (unsigned char*)(ws + 17344); // 319764 B
    float* lossbuf        = (float*)(ws + 337152);        // 4096 B
    float* xpart          = (float*)(ws + 341248);        // 8*2*256*256*4 = 4194304 B
    float* pmax           = (float*)(ws + 341248);        // overlay on xpart (100 KB,
                                                          // consumed by K2 before K4 writes)
    float* wt             = (float*)(ws + 341248 + 4194304); // 2359296 B
    const size_t WS_NEED = 341248 + 4194304 + 2359296;    // 6894848

    if (ws_size >= WS_NEED) {
        // 6-launch pipeline, no device-wide barriers (round-8 lesson:
        // software grid barrier ≈ 100 µs/barrier on MI355X — recompute instead)
        k1_bmax_wtrans<<<dim3(NBLK + WTBLK, 2), 256, 0, stream>>>(anchors, gt, w_in, pmax, wt);
        k2_label<<<dim3(NBLK, 2), 256, 0, stream>>>(anchors, gt, pmax, packed, blk_cnt);
        k3_select<<<dim3(NBLK, 2), 256, 0, stream>>>(packed, blk_cnt, sel, sel_count);
        k_convT<8><<<dim3(64, 8, 2), 256, 0, stream>>>(f_p6, f_p5, f_p4, f_p3, f_p2,
                                                       wt, sel, sel_count, xpart);
        k_post<8><<<dim3(256, 2), 256, 0, stream>>>(xpart, anchors, gt, b_in,
                                                    w_obj, b_obj, w_del, b_del,
                                                    packed, sel, sel_count, lossbuf);
        k_final<<<1, 512, 0, stream>>>(lossbuf, sel_count, out);
    } else {
        // tiny-workspace fallback (round-3 proven)
        k_init<<<1, 64, 0, stream>>>(best, out);
        k_best<<<dim3(64, 2), 256, 0, stream>>>(anchors, gt, best);
        k_label_old<<<dim3(NBLK, 2), 256, 0, stream>>>(anchors, gt, best, packed, blk_cnt);
        k3_select<<<dim3(NBLK, 2), 256, 0, stream>>>(packed, blk_cnt, sel, sel_count);
        k_eval<<<128, 256, 0, stream>>>(f_p6, f_p5, f_p4, f_p3, f_p2,
                                        anchors, gt, w_in, b_in, w_obj, b_obj,
                                        w_del, b_del, packed, sel, sel_count, out);
    }
}

// Round 10
// 63.068 us; speedup vs baseline: 4.4958x; 1.0957x over previous
//
#include <hip/hip_runtime.h>
#include <hip/hip_bf16.h>
#include <math.h>

#define A_TOTAL 159882
#define NGT 20
#define NBLK 625   // ceil(A_TOTAL/256)
#define WTBLK 288  // extra blocks (x2 imgs) for weight transpose in K1

// level geometry: p6(13) p5(25) p4(50) p3(100) p2(200), 3 anchors/pos
// cumulative anchor offsets: 0, 507, 2382, 9882, 39882, 159882

__device__ __forceinline__ float iou_one(float ax1, float ay1, float ax2, float ay2,
                                         float gx1, float gy1, float gx2, float gy2) {
    float a1 = (ax2 - ax1) * (ay2 - ay1);
    float a2 = (gx2 - gx1) * (gy2 - gy1);
    float ltx = fmaxf(ax1, gx1), lty = fmaxf(ay1, gy1);
    float rbx = fminf(ax2, gx2), rby = fminf(ay2, gy2);
    float w = fmaxf(rbx - ltx, 0.f), h = fmaxf(rby - lty, 0.f);
    float inter = w * h;
    return inter / (a1 + a2 - inter);
}

__device__ __forceinline__ void decode_anchor(int a, int& W, int& aid, int& y, int& x, int& lvl) {
    int off;
    if      (a < 507)   { off = 0;     W = 13;  lvl = 0; }
    else if (a < 2382)  { off = 507;   W = 25;  lvl = 1; }
    else if (a < 9882)  { off = 2382;  W = 50;  lvl = 2; }
    else if (a < 39882) { off = 9882;  W = 100; lvl = 3; }
    else                { off = 39882; W = 200; lvl = 4; }
    int rel = a - off;
    aid = rel % 3;
    int pos = rel / 3;
    y = pos / W; x = pos % W;
}

// ============ K1: wtrans (blocks >= NBLK) ∥ bmax + per-anchor mv/aux (blocks < NBLK) ============
__global__ __launch_bounds__(256) void k1_bmax_wtrans(
    const float* __restrict__ anchors, const float* __restrict__ gt,
    const float* __restrict__ w_in,
    float* __restrict__ pmax, float* __restrict__ mv, unsigned* __restrict__ aux,
    float* __restrict__ wt) {
    const int bx = blockIdx.x, img = blockIdx.y;
    const int tid = threadIdx.x;
    if (bx >= NBLK) {
        int idx = ((bx - NBLK) * 2 + img) * 256 + tid;   // 0..147455
        int co = idx / 576, k4 = idx - co * 576;
        float4 v = *(const float4*)(w_in + (size_t)co * 2304 + k4 * 4);
        ((float4*)wt)[(size_t)k4 * 256 + co] = v;
        return;
    }
    __shared__ float sgt[NGT * 4];
    __shared__ float sred[4][NGT];
    __shared__ float pblk[NGT];
    if (tid < NGT * 4) sgt[tid] = gt[img * NGT * 4 + tid];
    __syncthreads();
    const int a = bx * 256 + tid;
    const bool act = a < A_TOTAL;
    float4 ab = make_float4(0.f, 0.f, 1.f, 1.f);
    if (act) ab = ((const float4*)anchors)[a];
    const int lane = tid & 63, wid = tid >> 6;
    float v[NGT];
    float mval = -1.f; int arg = 0;
    #pragma unroll
    for (int g = 0; g < NGT; g++) {
        float u = act ? iou_one(ab.x, ab.y, ab.z, ab.w,
                                sgt[g*4], sgt[g*4+1], sgt[g*4+2], sgt[g*4+3]) : 0.f;
        v[g] = u;
        if (u > mval) { mval = u; arg = g; }
    }
    #pragma unroll
    for (int g = 0; g < NGT; g++) {
        float u = v[g];
        #pragma unroll
        for (int o = 32; o > 0; o >>= 1) u = fmaxf(u, __shfl_down(u, o));
        if (lane == 0) sred[wid][g] = u;
    }
    __syncthreads();
    if (tid < NGT) {
        float u = fmaxf(fmaxf(sred[0][tid], sred[1][tid]),
                        fmaxf(sred[2][tid], sred[3][tid]));
        pblk[tid] = u;
        pmax[((size_t)img * NBLK + bx) * NGT + tid] = u;
    }
    __syncthreads();
    if (act) {
        unsigned mask = 0;
        #pragma unroll
        for (int g = 0; g < NGT; g++)
            if (v[g] == pblk[g] && v[g] > 0.f) mask |= (1u << g);
        mv[(size_t)img * A_TOTAL + a] = mval;
        aux[(size_t)img * A_TOTAL + a] = (mask << 5) | (unsigned)arg;
    }
}

// ============ K1b: tree-reduce 625 partials per (img, gt) -> best ============
__global__ void k_bred(const float* __restrict__ pmax, unsigned int* __restrict__ best) {
    const int g = blockIdx.x, img = blockIdx.y;
    const int tid = threadIdx.x;   // 256
    float v = 0.f;
    for (int i = tid; i < NBLK; i += 256)
        v = fmaxf(v, pmax[((size_t)img * NBLK + i) * NGT + g]);
    const int lane = tid & 63, wid = tid >> 6;
    #pragma unroll
    for (int o = 32; o > 0; o >>= 1) v = fmaxf(v, __shfl_down(v, o));
    __shared__ float r[4];
    if (lane == 0) r[wid] = v;
    __syncthreads();
    if (tid == 0)
        best[img * NGT + g] = __float_as_uint(fmaxf(fmaxf(r[0], r[1]), fmaxf(r[2], r[3])));
}

// ============ K2: label from stored mv/aux (no IoU recompute) ============
__global__ __launch_bounds__(256) void k2_label(
    const float* __restrict__ mv, const unsigned* __restrict__ aux,
    const float* __restrict__ pmax, const unsigned int* __restrict__ best,
    unsigned char* __restrict__ packed, unsigned int* __restrict__ blk_cnt) {
    const int img = blockIdx.y, blk = blockIdx.x;
    const int tid = threadIdx.x;
    const int lane = tid & 63, wid = tid >> 6;
    __shared__ float sbest[NGT], pblk[NGT];
    __shared__ int wp[4], wn[4];
    if (tid < NGT) {
        sbest[tid] = __uint_as_float(best[img * NGT + tid]);
        pblk[tid]  = pmax[((size_t)img * NBLK + blk) * NGT + tid];
    }
    __syncthreads();
    const int a = blk * 256 + tid;
    const bool act = a < A_TOTAL;
    int code = 2;
    if (act) {
        float mval = mv[(size_t)img * A_TOTAL + a];
        unsigned ax = aux[(size_t)img * A_TOTAL + a];
        unsigned mask = ax >> 5;
        bool lq = false;
        #pragma unroll
        for (int g = 0; g < NGT; g++)
            if (((mask >> g) & 1u) && (pblk[g] == sbest[g])) lq = true;
        if (lq || mval >= 0.7f) code = 1;
        else if (mval < 0.3f)   code = 0;
        packed[(size_t)img * A_TOTAL + a] = (unsigned char)((code << 5) | (ax & 31u));
    }
    unsigned long long bp = __ballot(act && code == 1);
    unsigned long long bn = __ballot(act && code == 0);
    if (lane == 0) { wp[wid] = __popcll(bp); wn[wid] = __popcll(bn); }
    __syncthreads();
    if (tid == 0) {
        unsigned int p = wp[0] + wp[1] + wp[2] + wp[3];
        unsigned int n = wn[0] + wn[1] + wn[2] + wn[3];
        blk_cnt[img * NBLK + blk] = (p << 16) | n;
    }
}

// ============ K3: select + per-block self-prefix (round-9 proven) ============
__global__ __launch_bounds__(256) void k3_select(
    const unsigned char* __restrict__ packed,
    const unsigned int* __restrict__ blk_cnt,
    int* __restrict__ sel, int* __restrict__ sel_count) {
    const int img = blockIdx.y, blk = blockIdx.x;
    const int tid = threadIdx.x;
    const int lane = tid & 63, wid = tid >> 6;
    __shared__ unsigned long long sscan[8];
    __shared__ int wcnt[8];

    unsigned long long tot = 0ULL, pre = 0ULL;
    const int j0 = tid * 3;
    #pragma unroll
    for (int j = 0; j < 3; j++) {
        int i = j0 + j;
        if (i < NBLK) {
            unsigned u = blk_cnt[img * NBLK + i];
            unsigned long long w = ((unsigned long long)(u >> 16) << 32) | (u & 0xFFFFu);
            tot += w;
            if (i < blk) pre += w;
        }
    }
    #pragma unroll
    for (int o = 32; o > 0; o >>= 1) {
        tot += __shfl_down(tot, o);
        pre += __shfl_down(pre, o);
    }
    if (lane == 0) { sscan[wid] = tot; sscan[4 + wid] = pre; }
    __syncthreads();
    unsigned long long tota = sscan[0] + sscan[1] + sscan[2] + sscan[3];
    unsigned long long prea = sscan[4] + sscan[5] + sscan[6] + sscan[7];
    int tp = (int)(tota >> 32), tn = (int)(tota & 0xFFFFFFFFull);
    int npos = min(tp, 128), capn = 256 - npos;
    if (blk == 0 && tid == 0) sel_count[img] = npos + min(tn, capn);
    int base_p = (int)(prea >> 32), base_n = (int)(prea & 0xFFFFFFFFull);

    const int a = blk * 256 + tid;
    const bool act = a < A_TOTAL;
    int code = act ? (packed[(size_t)img * A_TOTAL + a] >> 5) : 2;
    const bool isp = act && code == 1;
    const bool isn = act && code == 0;
    unsigned long long bp = __ballot(isp);
    unsigned long long bn = __ballot(isn);
    if (lane == 0) { wcnt[wid] = __popcll(bp); wcnt[4 + wid] = __popcll(bn); }
    __syncthreads();
    const unsigned long long mlt = (1ULL << lane) - 1ULL;
    int rp = __popcll(bp & mlt), rn = __popcll(bn & mlt);
    for (int w = 0; w < 4; w++)
        if (w < wid) { rp += wcnt[w]; rn += wcnt[4 + w]; }
    if (isp) { int r = base_p + rp; if (r < npos) sel[img * 256 + r] = a | (1 << 30); }
    if (isn) { int r = base_n + rn; if (r < capn) sel[img * 256 + npos + r] = a; }
}

// ============ K4: conv partials — 8 anchors x 16-ci chunk (TRM=144) per block ============
__global__ __launch_bounds__(256) void k_convT16(
    const float* __restrict__ f0, const float* __restrict__ f1,
    const float* __restrict__ f2, const float* __restrict__ f3,
    const float* __restrict__ f4,
    const float* __restrict__ wt,
    const int* __restrict__ sel, const int* __restrict__ sel_count,
    float* __restrict__ xpart) {
    const int img = blockIdx.z;          // grid (32, 16, 2)
    const int chunk = blockIdx.y;
    const int slot0 = blockIdx.x * 8;
    const int nsel = sel_count[img];
    if (slot0 >= nsel) return;

    __shared__ __align__(16) float patch[8][144];    // 4608 B
    __shared__ int sW[8], sY[8], sX[8], sAct[8];
    __shared__ const float* sfm[8];
    const int tid = threadIdx.x;

    if (tid < 8) {
        int slot = slot0 + tid;
        bool act = slot < nsel;
        int e = act ? sel[img * 256 + slot] : 0;
        int a = e & 0x3FFFFFFF;
        int W, aid, y, x, lvl;
        decode_anchor(a, W, aid, y, x, lvl);
        sW[tid] = W; sY[tid] = y; sX[tid] = x; sAct[tid] = act ? 1 : 0;
        sfm[tid] = (lvl == 0 ? f0 : lvl == 1 ? f1 : lvl == 2 ? f2 : lvl == 3 ? f3 : f4);
    }
    __syncthreads();

    for (int p = tid; p < 8 * 144; p += 256) {
        int aa = p / 144;
        int idx = p - aa * 144;
        int cil = idx / 9;
        int r = idx - cil * 9;
        int ky = r / 3, kx = r - ky * 3;
        int W = sW[aa];
        int yy = sY[aa] + ky - 1, xx = sX[aa] + kx - 1;
        float v = 0.f;
        if (sAct[aa] && yy >= 0 && yy < W && xx >= 0 && xx < W) {
            int ci = chunk * 16 + cil;
            v = sfm[aa][(((size_t)img * 256 + ci) * W + yy) * W + xx];
        }
        patch[aa][idx] = v;
    }
    __syncthreads();

    const int c = tid;
    const float4* wt4 = (const float4*)wt + (size_t)(chunk * 36) * 256 + c;
    float acc[8] = {0.f, 0.f, 0.f, 0.f, 0.f, 0.f, 0.f, 0.f};
    #pragma unroll 4
    for (int i = 0; i < 36; i++) {
        float4 w = wt4[(size_t)i * 256];     // 1KB contiguous per wave
        #pragma unroll
        for (int aa = 0; aa < 8; aa++) {
            float4 q = ((const float4*)patch[aa])[i];   // uniform addr -> broadcast
            acc[aa] += w.x * q.x + w.y * q.y + w.z * q.z + w.w * q.w;
        }
    }
    #pragma unroll
    for (int aa = 0; aa < 8; aa++) {
        int slot = slot0 + aa;
        if (slot < nsel)
            xpart[(((size_t)img * 16 + chunk) * 256 + slot) * 256 + c] = acc[aa];
    }
}

// ============ K5: reduce 16 chunks + heads + per-anchor losses ============
__global__ __launch_bounds__(256) void k_post16(
    const float* __restrict__ xpart,
    const float* __restrict__ anchors, const float* __restrict__ gt,
    const float* __restrict__ b_in,
    const float* __restrict__ w_obj, const float* __restrict__ b_obj,
    const float* __restrict__ w_del, const float* __restrict__ b_del,
    const unsigned char* __restrict__ packed,
    const int* __restrict__ sel, const int* __restrict__ sel_count,
    float* __restrict__ lossbuf) {
    const int img = blockIdx.y;
    const int slot = blockIdx.x;
    const int nsel = sel_count[img];
    if (slot >= nsel) return;
    const int e = sel[img * 256 + slot];
    const int is_pos = (e >> 30) & 1;
    const int a = e & 0x3FFFFFFF;
    int W, aid, y, x, lvl;
    decode_anchor(a, W, aid, y, x, lvl);

    const int c = threadIdx.x;
    float s = b_in[c];
    #pragma unroll
    for (int ch = 0; ch < 16; ch++)
        s += xpart[(((size_t)img * 16 + ch) * 256 + slot) * 256 + c];
    float xf = fmaxf(s, 0.f);

    float part[5];
    part[0] = xf * w_obj[aid * 256 + c];
    #pragma unroll
    for (int j = 0; j < 4; j++) part[1 + j] = xf * w_del[(aid * 4 + j) * 256 + c];
    const int lane = c & 63, wid = c >> 6;
    __shared__ float red[5][4];
    #pragma unroll
    for (int o = 32; o > 0; o >>= 1)
        #pragma unroll
        for (int j = 0; j < 5; j++) part[j] += __shfl_down(part[j], o);
    if (lane == 0)
        #pragma unroll
        for (int j = 0; j < 5; j++) red[j][wid] = part[j];
    __syncthreads();

    if (c == 0) {
        float logit = red[0][0] + red[0][1] + red[0][2] + red[0][3] + b_obj[aid];
        float tgt = is_pos ? 1.f : 0.f;
        float bce = fmaxf(logit, 0.f) - logit * tgt + log1pf(expf(-fabsf(logit)));
        float l1 = 0.f;
        if (is_pos) {
            float d[4];
            #pragma unroll
            for (int j = 0; j < 4; j++)
                d[j] = red[1 + j][0] + red[1 + j][1] + red[1 + j][2] + red[1 + j][3] + b_del[aid * 4 + j];
            int m = packed[(size_t)img * A_TOTAL + a] & 31;
            const float* sp = anchors + (size_t)a * 4;
            const float* t = gt + (size_t)(img * NGT + m) * 4;
            float sw = sp[2] - sp[0], sh = sp[3] - sp[1];
            float scx = sp[0] + 0.5f * sw, scy = sp[1] + 0.5f * sh;
            float tw = t[2] - t[0], th = t[3] - t[1];
            float tcx = t[0] + 0.5f * tw, tcy = t[1] + 0.5f * th;
            float g0 = (tcx - scx) / sw, g1 = (tcy - scy) / sh;
            float g2 = logf(tw / sw),    g3 = logf(th / sh);
            l1 = fabsf(d[0] - g0) + fabsf(d[1] - g1) + fabsf(d[2] - g2) + fabsf(d[3] - g3);
        }
        lossbuf[(img * 256 + slot) * 2 + 0] = bce;
        lossbuf[(img * 256 + slot) * 2 + 1] = l1;
    }
}

// ============ K6: deterministic final reduction ============
__global__ void k_final(const float* __restrict__ lossbuf,
                        const int* __restrict__ sel_count,
                        float* __restrict__ out) {
    const int t = threadIdx.x;      // 512 threads
    const int img = t >> 8, slot = t & 255;
    float bce = 0.f, l1 = 0.f;
    if (slot < sel_count[img]) {
        bce = lossbuf[t * 2 + 0];
        l1  = lossbuf[t * 2 + 1];
    }
    const int lane = t & 63, wid = t >> 6;
    #pragma unroll
    for (int o = 32; o > 0; o >>= 1) {
        bce += __shfl_down(bce, o);
        l1  += __shfl_down(l1, o);
    }
    __shared__ float rb[8], rl[8];
    if (lane == 0) { rb[wid] = bce; rl[wid] = l1; }
    __syncthreads();
    if (t == 0) {
        float sb = 0.f, sl = 0.f;
        #pragma unroll
        for (int w = 0; w < 8; w++) { sb += rb[w]; sl += rl[w]; }
        out[0] = 0.5f * sb;
        out[1] = 0.5f * sl;
    }
}

// ============ minimal fallback (round-3 proven) for tiny workspace ============
__global__ void k_init(unsigned int* best, float* out) {
    int t = threadIdx.x;
    if (t < 2 * NGT) best[t] = 0u;
    if (t < 2) out[t] = 0.f;
}

__global__ void k_best(const float* __restrict__ anchors, const float* __restrict__ gt,
                       unsigned int* best) {
    const int img = blockIdx.y;
    __shared__ float sgt[NGT * 4];
    __shared__ float sred[4][NGT];
    const int tid = threadIdx.x;
    if (tid < NGT * 4) sgt[tid] = gt[img * NGT * 4 + tid];
    __syncthreads();
    float vmax[NGT];
    #pragma unroll
    for (int g = 0; g < NGT; g++) vmax[g] = 0.f;
    const int stride = gridDim.x * blockDim.x;
    for (int a = blockIdx.x * blockDim.x + tid; a < A_TOTAL; a += stride) {
        float4 ab = ((const float4*)anchors)[a];
        #pragma unroll
        for (int g = 0; g < NGT; g++) {
            float v = iou_one(ab.x, ab.y, ab.z, ab.w,
                              sgt[g * 4], sgt[g * 4 + 1], sgt[g * 4 + 2], sgt[g * 4 + 3]);
            vmax[g] = fmaxf(vmax[g], v);
        }
    }
    const int lane = tid & 63, wid = tid >> 6;
    #pragma unroll
    for (int g = 0; g < NGT; g++) {
        float v = vmax[g];
        #pragma unroll
        for (int o = 32; o > 0; o >>= 1) v = fmaxf(v, __shfl_down(v, o));
        if (lane == 0) sred[wid][g] = v;
    }
    __syncthreads();
    if (tid < NGT) {
        float v = fmaxf(fmaxf(sred[0][tid], sred[1][tid]),
                        fmaxf(sred[2][tid], sred[3][tid]));
        atomicMax(&best[img * NGT + tid], __float_as_uint(v));
    }
}

__global__ void k_label_old(const float* __restrict__ anchors, const float* __restrict__ gt,
                            const unsigned int* __restrict__ best,
                            unsigned char* packed, unsigned int* blk_cnt) {
    const int img = blockIdx.y;
    __shared__ float sgt[NGT * 4];
    __shared__ unsigned int sbest[NGT];
    __shared__ int wp[4], wn[4];
    const int tid = threadIdx.x;
    if (tid < NGT * 4) sgt[tid] = gt[img * NGT * 4 + tid];
    if (tid < NGT) sbest[tid] = best[img * NGT + tid];
    __syncthreads();
    const int a = blockIdx.x * blockDim.x + tid;
    const bool act = a < A_TOTAL;
    int code = 2;
    if (act) {
        float4 ab = ((const float4*)anchors)[a];
        float mval = -1.f; int arg = 0; bool lq = false;
        #pragma unroll
        for (int g = 0; g < NGT; g++) {
            float v = iou_one(ab.x, ab.y, ab.z, ab.w,
                              sgt[g * 4], sgt[g * 4 + 1], sgt[g * 4 + 2], sgt[g * 4 + 3]);
            if (v > mval) { mval = v; arg = g; }
            if (__float_as_uint(v) == sbest[g] && v > 0.f) lq = true;
        }
        if (lq || mval >= 0.7f) code = 1;
        else if (mval < 0.3f)   code = 0;
        packed[(size_t)img * A_TOTAL + a] = (unsigned char)((code << 5) | arg);
    }
    unsigned long long bp = __ballot(act && code == 1);
    unsigned long long bn = __ballot(act && code == 0);
    const int lane = tid & 63, wid = tid >> 6;
    if (lane == 0) { wp[wid] = __popcll(bp); wn[wid] = __popcll(bn); }
    __syncthreads();
    if (tid == 0) {
        unsigned int p = wp[0] + wp[1] + wp[2] + wp[3];
        unsigned int n = wn[0] + wn[1] + wn[2] + wn[3];
        blk_cnt[img * NBLK + blockIdx.x] = (p << 16) | n;
    }
}

__global__ __launch_bounds__(256) void k_eval(
    const float* __restrict__ f0, const float* __restrict__ f1,
    const float* __restrict__ f2, const float* __restrict__ f3,
    const float* __restrict__ f4,
    const float* __restrict__ anchors, const float* __restrict__ gt,
    const float* __restrict__ w_in, const float* __restrict__ b_in,
    const float* __restrict__ w_obj, const float* __restrict__ b_obj,
    const float* __restrict__ w_del, const float* __restrict__ b_del,
    const unsigned char* __restrict__ packed,
    const int* __restrict__ sel, const int* __restrict__ sel_count,
    float* out) {
    const int img = blockIdx.x >> 6;
    const int slot0 = (blockIdx.x & 63) * 4;
    const int nsel = sel_count[img];
    if (slot0 >= nsel) return;

    __shared__ __align__(16) float patch[4][2304];
    __shared__ float red[4][5][4];
    __shared__ float lsum[2];
    const int c = threadIdx.x;
    if (c < 2) lsum[c] = 0.f;

    bool actv[4]; int av[4], aidv[4], isposv[4];
    #pragma unroll
    for (int aa = 0; aa < 4; aa++) {
        int slot = slot0 + aa;
        bool act = slot < nsel;
        actv[aa] = act;
        int e = act ? sel[img * 256 + slot] : 0;
        isposv[aa] = (e >> 30) & 1;
        int a = e & 0x3FFFFFFF;
        av[aa] = a;
        int W, aid, y, x, lvl;
        decode_anchor(a, W, aid, y, x, lvl);
        aidv[aa] = aid;
        const float* fm = lvl == 0 ? f0 : lvl == 1 ? f1 : lvl == 2 ? f2 : lvl == 3 ? f3 : f4;
        const float* ch = fm + ((size_t)img * 256 + c) * W * W;
        #pragma unroll
        for (int ky = 0; ky < 3; ky++)
            #pragma unroll
            for (int kx = 0; kx < 3; kx++) {
                int yy = y + ky - 1, xx = x + kx - 1;
                float v = (act && yy >= 0 && yy < W && xx >= 0 && xx < W) ? ch[yy * W + xx] : 0.f;
                patch[aa][c * 9 + ky * 3 + kx] = v;
            }
    }
    __syncthreads();

    const float bi = b_in[c];
    float acc0 = bi, acc1 = bi, acc2 = bi, acc3 = bi;
    const float4* wr = (const float4*)(w_in + (size_t)c * 2304);
    const float4* p0 = (const float4*)patch[0];
    const float4* p1 = (const float4*)patch[1];
    const float4* p2 = (const float4*)patch[2];
    const float4* p3 = (const float4*)patch[3];
    #pragma unroll 4
    for (int i = 0; i < 576; i++) {
        float4 w = wr[i];
        float4 q;
        q = p0[i]; acc0 += w.x * q.x + w.y * q.y + w.z * q.z + w.w * q.w;
        q = p1[i]; acc1 += w.x * q.x + w.y * q.y + w.z * q.z + w.w * q.w;
        q = p2[i]; acc2 += w.x * q.x + w.y * q.y + w.z * q.z + w.w * q.w;
        q = p3[i]; acc3 += w.x * q.x + w.y * q.y + w.z * q.z + w.w * q.w;
    }
    float xf[4] = { fmaxf(acc0, 0.f), fmaxf(acc1, 0.f), fmaxf(acc2, 0.f), fmaxf(acc3, 0.f) };

    float part[4][5];
    #pragma unroll
    for (int aa = 0; aa < 4; aa++) {
        part[aa][0] = xf[aa] * w_obj[aidv[aa] * 256 + c];
        #pragma unroll
        for (int j = 0; j < 4; j++)
            part[aa][1 + j] = xf[aa] * w_del[(aidv[aa] * 4 + j) * 256 + c];
    }
    const int lane = c & 63, wid = c >> 6;
    #pragma unroll
    for (int o = 32; o > 0; o >>= 1)
        #pragma unroll
        for (int aa = 0; aa < 4; aa++)
            #pragma unroll
            for (int j = 0; j < 5; j++)
                part[aa][j] += __shfl_down(part[aa][j], o);
    if (lane == 0)
        #pragma unroll
        for (int aa = 0; aa < 4; aa++)
            #pragma unroll
            for (int j = 0; j < 5; j++)
                red[aa][j][wid] = part[aa][j];
    __syncthreads();

    if (c < 4 && actv[c]) {
        const int aa = c;
        float logit = red[aa][0][0] + red[aa][0][1] + red[aa][0][2] + red[aa][0][3] + b_obj[aidv[aa]];
        float tgt = isposv[aa] ? 1.f : 0.f;
        float bce = fmaxf(logit, 0.f) - logit * tgt + log1pf(expf(-fabsf(logit)));
        atomicAdd(&lsum[0], bce);
        if (isposv[aa]) {
            float d[4];
            #pragma unroll
            for (int j = 0; j < 4; j++)
                d[j] = red[aa][1 + j][0] + red[aa][1 + j][1] + red[aa][1 + j][2] + red[aa][1 + j][3]
                       + b_del[aidv[aa] * 4 + j];
            int a = av[aa];
            int m = packed[(size_t)img * A_TOTAL + a] & 31;
            const float* s = anchors + (size_t)a * 4;
            const float* t = gt + (size_t)(img * NGT + m) * 4;
            float sw = s[2] - s[0], sh = s[3] - s[1];
            float scx = s[0] + 0.5f * sw, scy = s[1] + 0.5f * sh;
            float tw = t[2] - t[0], th = t[3] - t[1];
            float tcx = t[0] + 0.5f * tw, tcy = t[1] + 0.5f * th;
            float g0 = (tcx - scx) / sw, g1 = (tcy - scy) / sh;
            float g2 = logf(tw / sw),    g3 = logf(th / sh);
            float l1 = fabsf(d[0] - g0) + fabsf(d[1] - g1) + fabsf(d[2] - g2) + fabsf(d[3] - g3);
            atomicAdd(&lsum[1], l1);
        }
    }
    __syncthreads();
    if (c == 0) {
        atomicAdd(&out[0], 0.5f * lsum[0]);
        atomicAdd(&out[1], 0.5f * lsum[1]);
    }
}

extern "C" void kernel_launch(void* const* d_in, const int* in_sizes, int n_in,
                              void* d_out, int out_size, void* d_ws, size_t ws_size,
                              hipStream_t stream) {
    const float* f_p6 = (const float*)d_in[0];
    const float* f_p5 = (const float*)d_in[1];
    const float* f_p4 = (const float*)d_in[2];
    const float* f_p3 = (const float*)d_in[3];
    const float* f_p2 = (const float*)d_in[4];
    const float* anchors = (const float*)d_in[5];
    const float* gt      = (const float*)d_in[6];
    const float* w_in  = (const float*)d_in[7];
    const float* b_in  = (const float*)d_in[8];
    const float* w_obj = (const float*)d_in[9];
    const float* b_obj = (const float*)d_in[10];
    const float* w_del = (const float*)d_in[11];
    const float* b_del = (const float*)d_in[12];
    float* out = (float*)d_out;
    char* ws = (char*)d_ws;

    // workspace layout
    unsigned int* best    = (unsigned int*)(ws + 0);        // 160 B
    int* sel_count        = (int*)(ws + 168);               // 8 B
    int* sel              = (int*)(ws + 192);               // 2048 B
    unsigned int* blk_cnt = (unsigned int*)(ws + 2240);     // 5000 B
    unsigned char* packed = (unsigned char*)(ws + 17344);   // 319764 B
    float* lossbuf        = (float*)(ws + 337152);          // 4096 B
    float* mv             = (float*)(ws + 341248);          // 1279056 B
    unsigned* aux         = (unsigned*)(ws + 1620352);      // 1279056 B
    float* pmax           = (float*)(ws + 2899456);         // 100000 B
    float* xpart          = (float*)(ws + 2999552);         // 16*2*256*256*4 = 8388608 B
    float* wt             = (float*)(ws + 11388160);        // 2359296 B
    const size_t WS_NEED  = 13747456;

    if (ws_size >= WS_NEED) {
        // 7-launch pipeline. Round-8/9 lessons: software grid barriers ≈100 µs
        // each (never); per-launch overhead ~1-2 µs, so tiny kernels (bred) are
        // cheaper as launches than as per-block recompute.
        k1_bmax_wtrans<<<dim3(NBLK + WTBLK, 2), 256, 0, stream>>>(anchors, gt, w_in,
                                                                  pmax, mv, aux, wt);
        k_bred<<<dim3(NGT, 2), 256, 0, stream>>>(pmax, best);
        k2_label<<<dim3(NBLK, 2), 256, 0, stream>>>(mv, aux, pmax, best, packed, blk_cnt);
        k3_select<<<dim3(NBLK, 2), 256, 0, stream>>>(packed, blk_cnt, sel, sel_count);
        k_convT16<<<dim3(32, 16, 2), 256, 0, stream>>>(f_p6, f_p5, f_p4, f_p3, f_p2,
                                                       wt, sel, sel_count, xpart);
        k_post16<<<dim3(256, 2), 256, 0, stream>>>(xpart, anchors, gt, b_in,
                                                   w_obj, b_obj, w_del, b_del,
                                                   packed, sel, sel_count, lossbuf);
        k_final<<<1, 512, 0, stream>>>(lossbuf, sel_count, out);
    } else {
        // tiny-workspace fallback (round-3 proven)
        k_init<<<1, 64, 0, stream>>>(best, out);
        k_best<<<dim3(64, 2), 256, 0, stream>>>(anchors, gt, best);
        k_label_old<<<dim3(NBLK, 2), 256, 0, stream>>>(anchors, gt, best, packed, blk_cnt);
        k3_select<<<dim3(NBLK, 2), 256, 0, stream>>>(packed, blk_cnt, sel, sel_count);
        k_eval<<<128, 256, 0, stream>>>(f_p6, f_p5, f_p4, f_p3, f_p2,
                                        anchors, gt, w_in, b_in, w_obj, b_obj,
                                        w_del, b_del, packed, sel, sel_count, out);
    }
}